// Round 1
// baseline (1493.712 us; speedup 1.0000x reference)
//
#include <hip/hip_runtime.h>

namespace {
constexpr int kB  = 8;
constexpr int kS  = 1024;
constexpr int kH  = 1024;
constexpr int kNH = 16;
constexpr int kHD = 64;
constexpr int kBH = kB * kNH;            // 128 head-batches
constexpr int kRows = kBH * kS;          // 131072 rows per projected tensor
}

// ---------------------------------------------------------------------------
// Kernel 1: fused QKV projection GEMM (fp32 baseline).
// C[m,n] = sum_k hs[m,k]*W[k,n] + b[n], scattered to [B,NH,S,HD] layout.
// Tile 128x128x16, 256 threads, 8x8 per thread as 2x2 sub-blocks of 4
// (keeps LDS compute reads as aligned float4 with <=2-way bank aliasing).
// ---------------------------------------------------------------------------
__global__ __launch_bounds__(256) void qkv_gemm_kernel(
    const float* __restrict__ hs,
    const float* __restrict__ Wq, const float* __restrict__ bq,
    const float* __restrict__ Wk, const float* __restrict__ bk,
    const float* __restrict__ Wv, const float* __restrict__ bv,
    float* __restrict__ qw, float* __restrict__ kw, float* __restrict__ vw)
{
    const float* W; const float* bias; float* out;
    switch (blockIdx.z) {
        case 0:  W = Wq; bias = bq; out = qw; break;
        case 1:  W = Wk; bias = bk; out = kw; break;
        default: W = Wv; bias = bv; out = vw; break;
    }

    __shared__ float As[16][132];   // [k][m], padded
    __shared__ float Bs[16][132];   // [k][n], padded

    const int tid = threadIdx.x;
    const int tx  = tid & 15;
    const int ty  = tid >> 4;
    const int m0  = blockIdx.y * 128;
    const int n0  = blockIdx.x * 128;

    float acc[8][8];
#pragma unroll
    for (int i = 0; i < 8; ++i)
#pragma unroll
        for (int j = 0; j < 8; ++j) acc[i][j] = 0.0f;

    for (int kt = 0; kt < kH; kt += 16) {
        __syncthreads();   // previous iteration's compute done before overwrite
        // A tile: 128 m x 16 k, transposed into As[k][m]
#pragma unroll
        for (int i = 0; i < 2; ++i) {
            int f4 = tid + i * 256;          // 0..511 float4 slots
            int r  = f4 >> 2;                // m offset 0..127
            int cb = (f4 & 3) * 4;           // k offset 0,4,8,12
            float4 a = *(const float4*)(hs + (size_t)(m0 + r) * kH + kt + cb);
            As[cb + 0][r] = a.x;
            As[cb + 1][r] = a.y;
            As[cb + 2][r] = a.z;
            As[cb + 3][r] = a.w;
        }
        // B tile: 16 k x 128 n (natural layout)
#pragma unroll
        for (int i = 0; i < 2; ++i) {
            int f4 = tid + i * 256;
            int r  = f4 >> 5;                // k 0..15
            int c  = (f4 & 31) * 4;          // n 0..124
            float4 b = *(const float4*)(W + (size_t)(kt + r) * kH + n0 + c);
            Bs[r][c + 0] = b.x;
            Bs[r][c + 1] = b.y;
            Bs[r][c + 2] = b.z;
            Bs[r][c + 3] = b.w;
        }
        __syncthreads();

#pragma unroll
        for (int kk = 0; kk < 16; ++kk) {
            float a[8], b[8];
            float4 t;
            t = *(const float4*)&As[kk][ty * 4];       a[0]=t.x; a[1]=t.y; a[2]=t.z; a[3]=t.w;
            t = *(const float4*)&As[kk][64 + ty * 4];  a[4]=t.x; a[5]=t.y; a[6]=t.z; a[7]=t.w;
            t = *(const float4*)&Bs[kk][tx * 4];       b[0]=t.x; b[1]=t.y; b[2]=t.z; b[3]=t.w;
            t = *(const float4*)&Bs[kk][64 + tx * 4];  b[4]=t.x; b[5]=t.y; b[6]=t.z; b[7]=t.w;
#pragma unroll
            for (int i = 0; i < 8; ++i)
#pragma unroll
                for (int j = 0; j < 8; ++j)
                    acc[i][j] += a[i] * b[j];
        }
    }

    // Epilogue: bias + coalesced float4 scatter to [B,NH,S,HD]
    const float4 bias0 = *(const float4*)(bias + n0 + tx * 4);
    const float4 bias1 = *(const float4*)(bias + n0 + 64 + tx * 4);
    const int h0 = n0 >> 6;   // first head of this column block (n0 multiple of 128)
#pragma unroll
    for (int i = 0; i < 8; ++i) {
        int m  = m0 + (i < 4 ? ty * 4 + i : 64 + ty * 4 + (i - 4));
        int bb = m >> 10;
        int s  = m & 1023;
        float4 o0, o1;
        o0.x = acc[i][0] + bias0.x; o0.y = acc[i][1] + bias0.y;
        o0.z = acc[i][2] + bias0.z; o0.w = acc[i][3] + bias0.w;
        o1.x = acc[i][4] + bias1.x; o1.y = acc[i][5] + bias1.y;
        o1.z = acc[i][6] + bias1.z; o1.w = acc[i][7] + bias1.w;
        *(float4*)(out + ((size_t)((bb * kNH + h0    ) * kS + s)) * kHD + tx * 4) = o0;
        *(float4*)(out + ((size_t)((bb * kNH + h0 + 1) * kS + s)) * kHD + tx * 4) = o1;
    }
}

// ---------------------------------------------------------------------------
// Kernel 2: context gating. One wave per (gate, b, h, s) row; lane = d.
// ce_q = ce @ Wc + bc ; lam = sigmoid(ce_q.wlc + x.wlx) ; x = (1-lam)x + lam ce_q
// In-place update of q / k workspace.
// ---------------------------------------------------------------------------
__global__ __launch_bounds__(256) void gate_kernel(
    const float* __restrict__ ce_full,   // [B,S,H]
    const float* __restrict__ Wcq, const float* __restrict__ bcq,
    const float* __restrict__ Wck, const float* __restrict__ bck,
    const float* __restrict__ wlqc, const float* __restrict__ wlqq,
    const float* __restrict__ wlkc, const float* __restrict__ wlkk,
    float* __restrict__ qw, float* __restrict__ kw)
{
    const int wave = blockIdx.x * 4 + (threadIdx.x >> 6);  // 0..262143
    const int lane = threadIdx.x & 63;
    const int gate = wave >> 17;                 // blocks 0..32767 q, rest k
    const int row  = wave & (kRows - 1);         // (b*16+h)*1024 + s

    const float* Wc  = gate ? Wck  : Wcq;
    const float* bc  = gate ? bck  : bcq;
    const float* wlc = gate ? wlkc : wlqc;
    const float* wlx = gate ? wlkk : wlqq;
    float* xw        = gate ? kw   : qw;

    // stage the 64x64 weight in LDS (all waves in a block share the gate)
    __shared__ float Wls[kHD * kHD];
    for (int i = threadIdx.x; i < kHD * kHD; i += 256) Wls[i] = Wc[i];
    __syncthreads();

    const int s  = row & 1023;
    const int bh = row >> 10;
    const int h  = bh & 15;
    const int bb = bh >> 4;

    const float ce = ce_full[((size_t)(bb * kS + s)) * kH + (h << 6) + lane];
    const float x  = xw[(size_t)row * kHD + lane];

    float ceq = bc[lane];
#pragma unroll
    for (int e = 0; e < kHD; ++e) {
        float ce_e = __shfl(ce, e, 64);
        ceq += ce_e * Wls[e * kHD + lane];
    }

    float t = ceq * wlc[lane] + x * wlx[lane];
#pragma unroll
    for (int off = 32; off > 0; off >>= 1) t += __shfl_xor(t, off, 64);
    const float lam = 1.0f / (1.0f + __expf(-t));

    xw[(size_t)row * kHD + lane] = (1.0f - lam) * x + lam * ceq;
}

// ---------------------------------------------------------------------------
// Kernel 3: flash-style attention, fp32. Block = 256 threads (16x16),
// 64 Q-rows per block, 16 K/V tiles of 64, online softmax, 4x4 per thread.
// Q,K stored transposed in LDS ([d][row]) so QK^T reads are float4.
// ---------------------------------------------------------------------------
__global__ __launch_bounds__(256) void flash_attn_kernel(
    const float* __restrict__ qw, const float* __restrict__ kw,
    const float* __restrict__ vw, const float* __restrict__ mask,
    float* __restrict__ out)
{
    __shared__ float Qt[64][68];   // [d][q-row]
    __shared__ float Kt[64][68];   // [d][k-row]
    __shared__ float Vs[64][68];   // [k-row][d]
    __shared__ float Ps[64][65];   // [q-row][k-row]

    const int tid = threadIdx.x;
    const int tx  = tid & 15;
    const int ty  = tid >> 4;
    const int bh  = blockIdx.y;
    const int bb  = bh >> 4;
    const int h   = bh & 15;
    const int q0  = blockIdx.x * 64;

    const float* Qp = qw + (size_t)bh * kS * kHD;
    const float* Kp = kw + (size_t)bh * kS * kHD;
    const float* Vp = vw + (size_t)bh * kS * kHD;
    const float* mp = mask + bb * kS;

    // load Q tile transposed
#pragma unroll
    for (int i = 0; i < 4; ++i) {
        int f4 = tid + i * 256;          // 0..1023
        int r  = f4 >> 4;                // row 0..63
        int cb = (f4 & 15) * 4;          // d base
        float4 q = *(const float4*)(Qp + (size_t)(q0 + r) * kHD + cb);
        Qt[cb + 0][r] = q.x; Qt[cb + 1][r] = q.y;
        Qt[cb + 2][r] = q.z; Qt[cb + 3][r] = q.w;
    }

    float o[4][4];
    float m_i[4], l_i[4];
#pragma unroll
    for (int i = 0; i < 4; ++i) {
        m_i[i] = -1e30f; l_i[i] = 0.0f;
#pragma unroll
        for (int j = 0; j < 4; ++j) o[i][j] = 0.0f;
    }

    for (int jt = 0; jt < kS; jt += 64) {
        __syncthreads();   // previous tile's compute done before LDS overwrite
#pragma unroll
        for (int i = 0; i < 4; ++i) {
            int f4 = tid + i * 256;
            int r  = f4 >> 4;
            int cb = (f4 & 15) * 4;
            float4 k = *(const float4*)(Kp + (size_t)(jt + r) * kHD + cb);
            Kt[cb + 0][r] = k.x; Kt[cb + 1][r] = k.y;
            Kt[cb + 2][r] = k.z; Kt[cb + 3][r] = k.w;
            float4 v = *(const float4*)(Vp + (size_t)(jt + r) * kHD + cb);
            Vs[r][cb + 0] = v.x; Vs[r][cb + 1] = v.y;
            Vs[r][cb + 2] = v.z; Vs[r][cb + 3] = v.w;
        }
        __syncthreads();

        // S = Q K^T
        float sc[4][4];
#pragma unroll
        for (int i = 0; i < 4; ++i)
#pragma unroll
            for (int j = 0; j < 4; ++j) sc[i][j] = 0.0f;

#pragma unroll 8
        for (int d = 0; d < 64; ++d) {
            float4 qa = *(const float4*)&Qt[d][ty * 4];
            float4 kb = *(const float4*)&Kt[d][tx * 4];
            float a[4] = {qa.x, qa.y, qa.z, qa.w};
            float b[4] = {kb.x, kb.y, kb.z, kb.w};
#pragma unroll
            for (int i = 0; i < 4; ++i)
#pragma unroll
                for (int j = 0; j < 4; ++j)
                    sc[i][j] += a[i] * b[j];
        }

        float mask4[4];
#pragma unroll
        for (int j = 0; j < 4; ++j) mask4[j] = mp[jt + tx * 4 + j];

        // online softmax update (row stats replicated across the 16 tx lanes)
#pragma unroll
        for (int i = 0; i < 4; ++i) {
            float mx = -1e30f;
#pragma unroll
            for (int j = 0; j < 4; ++j) {
                sc[i][j] = sc[i][j] * 0.125f + mask4[j];
                mx = fmaxf(mx, sc[i][j]);
            }
#pragma unroll
            for (int off = 1; off < 16; off <<= 1)
                mx = fmaxf(mx, __shfl_xor(mx, off, 64));
            float mn    = fmaxf(m_i[i], mx);
            float alpha = __expf(m_i[i] - mn);
            float rs = 0.0f;
#pragma unroll
            for (int j = 0; j < 4; ++j) {
                sc[i][j] = __expf(sc[i][j] - mn);
                rs += sc[i][j];
            }
#pragma unroll
            for (int off = 1; off < 16; off <<= 1)
                rs += __shfl_xor(rs, off, 64);
            l_i[i] = l_i[i] * alpha + rs;
            m_i[i] = mn;
#pragma unroll
            for (int j = 0; j < 4; ++j) o[i][j] *= alpha;
        }

        // stage P for the cross-thread PV product
#pragma unroll
        for (int i = 0; i < 4; ++i)
#pragma unroll
            for (int j = 0; j < 4; ++j)
                Ps[ty * 4 + i][tx * 4 + j] = sc[i][j];
        __syncthreads();

        // O += P V
#pragma unroll 8
        for (int c = 0; c < 64; ++c) {
            float p[4];
#pragma unroll
            for (int i = 0; i < 4; ++i) p[i] = Ps[ty * 4 + i][c];
            float4 vv = *(const float4*)&Vs[c][tx * 4];
            float v[4] = {vv.x, vv.y, vv.z, vv.w};
#pragma unroll
            for (int i = 0; i < 4; ++i)
#pragma unroll
                for (int j = 0; j < 4; ++j)
                    o[i][j] += p[i] * v[j];
        }
    }

    // epilogue: normalize and write [B,S,NH,HD] (= [B,S,H])
#pragma unroll
    for (int i = 0; i < 4; ++i) {
        int sg = q0 + ty * 4 + i;
        float inv = 1.0f / l_i[i];
        float4 r;
        r.x = o[i][0] * inv; r.y = o[i][1] * inv;
        r.z = o[i][2] * inv; r.w = o[i][3] * inv;
        *(float4*)(out + ((size_t)(bb * kS + sg)) * kH + (h << 6) + tx * 4) = r;
    }
}

// ---------------------------------------------------------------------------
extern "C" void kernel_launch(void* const* d_in, const int* in_sizes, int n_in,
                              void* d_out, int out_size, void* d_ws, size_t ws_size,
                              hipStream_t stream) {
    (void)in_sizes; (void)n_in; (void)out_size; (void)ws_size;

    const float* hs   = (const float*)d_in[0];
    const float* mask = (const float*)d_in[1];
    const float* ce   = (const float*)d_in[2];
    const float* Wq   = (const float*)d_in[3];
    const float* bq   = (const float*)d_in[4];
    const float* Wk   = (const float*)d_in[5];
    const float* bk   = (const float*)d_in[6];
    const float* Wv   = (const float*)d_in[7];
    const float* bv   = (const float*)d_in[8];
    const float* Wcq  = (const float*)d_in[9];
    const float* bcq  = (const float*)d_in[10];
    const float* Wck  = (const float*)d_in[11];
    const float* bck  = (const float*)d_in[12];
    const float* wlqc = (const float*)d_in[13];
    const float* wlqq = (const float*)d_in[14];
    const float* wlkc = (const float*)d_in[15];
    const float* wlkk = (const float*)d_in[16];
    float* out = (float*)d_out;

    float* qw = (float*)d_ws;                       // [B,NH,S,HD]
    float* kw = qw + (size_t)kRows * kHD;
    float* vw = kw + (size_t)kRows * kHD;           // total 96 MB of d_ws

    qkv_gemm_kernel<<<dim3(kH / 128, (kB * kS) / 128, 3), 256, 0, stream>>>(
        hs, Wq, bq, Wk, bk, Wv, bv, qw, kw, vw);

    gate_kernel<<<dim3(2 * kRows / 4), 256, 0, stream>>>(
        ce, Wcq, bcq, Wck, bck, wlqc, wlqq, wlkc, wlkk, qw, kw);

    flash_attn_kernel<<<dim3(kS / 64, kBH), 256, 0, stream>>>(
        qw, kw, vw, mask, out);
}

// Round 2
// 524.308 us; speedup vs baseline: 2.8489x; 2.8489x over previous
//
#include <hip/hip_runtime.h>

typedef _Float16 f16;
typedef f16   f16x8 __attribute__((ext_vector_type(8)));
typedef float f32x4 __attribute__((ext_vector_type(4)));

namespace {
constexpr int kB  = 8;
constexpr int kS  = 1024;
constexpr int kH  = 1024;
constexpr int kNH = 16;
constexpr int kHD = 64;
constexpr int kBH = kB * kNH;            // 128
constexpr int kRows = kBH * kS;          // 131072
}

// async global->LDS, 16B per lane; LDS dest = wave-uniform base + lane*16
__device__ __forceinline__ void async16(const f16* g, f16* l) {
    __builtin_amdgcn_global_load_lds(
        (const __attribute__((address_space(1))) unsigned int*)g,
        (__attribute__((address_space(3))) unsigned int*)l, 16, 0, 0);
}

// --- LDS chunk swizzles (16B chunks). Guarantee uniform bank-slot histogram
// per quad for MFMA fragment reads; invertible for global_load_lds staging. ---
// 64B rows (4 chunks/row), paired rows share a 128B bank group:
__device__ __forceinline__ int phys4(int m, int c) {
    return ((m >> 1) << 3) | ((((m & 1) << 2) | c) ^ ((m >> 1) & 7));
}
// 128B rows (8 chunks/row):
__device__ __forceinline__ int phys8(int m, int c) {
    return (m << 3) | (c ^ (m & 7));
}

// ---------------------------------------------------------------------------
// Cast hs fp32 -> f16
// ---------------------------------------------------------------------------
__global__ __launch_bounds__(256) void cast_hs_kernel(
    const float* __restrict__ hs, f16* __restrict__ out)
{
    int i = (blockIdx.x * 256 + threadIdx.x) * 8;
    float4 a = *(const float4*)(hs + i);
    float4 b = *(const float4*)(hs + i + 4);
    union { f16 h[8]; uint4 u; } pk;
    pk.h[0] = (f16)a.x; pk.h[1] = (f16)a.y; pk.h[2] = (f16)a.z; pk.h[3] = (f16)a.w;
    pk.h[4] = (f16)b.x; pk.h[5] = (f16)b.y; pk.h[6] = (f16)b.z; pk.h[7] = (f16)b.w;
    *(uint4*)(out + i) = pk.u;
}

// ---------------------------------------------------------------------------
// Transpose+cast W [K][N] fp32 -> Wt [N][K] f16 (B^T layout for the GEMM)
// ---------------------------------------------------------------------------
__global__ __launch_bounds__(256) void transpose_w_kernel(
    const float* __restrict__ Wq, const float* __restrict__ Wk,
    const float* __restrict__ Wv, f16* __restrict__ Wt)
{
    const float* W = (blockIdx.z == 0) ? Wq : (blockIdx.z == 1) ? Wk : Wv;
    f16* out = Wt + (size_t)blockIdx.z * kH * kH;
    __shared__ f16 T[64][72];
    const int tid = threadIdx.x;
    const int k0 = blockIdx.y * 64, n0 = blockIdx.x * 64;
#pragma unroll
    for (int i = 0; i < 4; ++i) {
        int idx = tid + i * 256;
        int r = idx >> 4, cb = (idx & 15) * 4;
        float4 v = *(const float4*)(W + (size_t)(k0 + r) * kH + n0 + cb);
        T[cb + 0][r] = (f16)v.x; T[cb + 1][r] = (f16)v.y;
        T[cb + 2][r] = (f16)v.z; T[cb + 3][r] = (f16)v.w;
    }
    __syncthreads();
#pragma unroll
    for (int i = 0; i < 4; ++i) {
        int idx = tid + i * 256;
        int r = idx >> 4, cb = (idx & 15) * 4;
        union { f16 h[4]; uint2 u; } pk;
#pragma unroll
        for (int j = 0; j < 4; ++j) pk.h[j] = T[r][cb + j];
        *(uint2*)(out + (size_t)(n0 + r) * kH + k0 + cb) = pk.u;
    }
}

// ---------------------------------------------------------------------------
// QKV GEMM, f16 MFMA (m97 structure). C = hs16 @ W (+bias).
// 128x128 tile, BK=32, 4 waves each 64x64 (4x4 tiles of 16x16x32).
// q/k written f16 head-split [bh][s][d]; V written TRANSPOSED f16 [bh][d][s].
// ---------------------------------------------------------------------------
__global__ __launch_bounds__(256) void qkv_gemm_f16(
    const f16* __restrict__ hs16, const f16* __restrict__ Wt,
    const float* __restrict__ bq, const float* __restrict__ bk,
    const float* __restrict__ bv,
    f16* __restrict__ q16, f16* __restrict__ k16, f16* __restrict__ vt)
{
    const int z = blockIdx.z;
    const f16* Bmat = Wt + (size_t)z * kH * kH;
    const float* bias = (z == 0) ? bq : (z == 1) ? bk : bv;

    __shared__ f16 Atile[128 * 32];
    __shared__ f16 Btile[128 * 32];

    const int tid = threadIdx.x;
    const int w = tid >> 6, lane = tid & 63;
    const int quad = lane >> 4, mh = lane & 15;
    const int wm = w >> 1, wn = w & 1;
    const int m0 = blockIdx.y * 128, n0 = blockIdx.x * 128;

    // staging source addresses (swizzle-inverted), 2 issues per wave per tile
    const f16* aptr[2]; const f16* bptr[2];
#pragma unroll
    for (int i = 0; i < 2; ++i) {
        int P = (w * 2 + i) * 64 + lane;
        int r2 = P >> 3, s = P & 7;
        int bb = s ^ (r2 & 7);
        int m = (r2 << 1) | (bb >> 2), c = bb & 3;
        aptr[i] = hs16 + (size_t)(m0 + m) * kH + c * 8;
        bptr[i] = Bmat + (size_t)(n0 + m) * kH + c * 8;
    }

    f32x4 acc[4][4];
#pragma unroll
    for (int i = 0; i < 4; ++i)
#pragma unroll
        for (int j = 0; j < 4; ++j) acc[i][j] = (f32x4){0.f, 0.f, 0.f, 0.f};

    // fragment read offsets (f16 units): chunk = quad, row per m/n tile
    int aoff[4], boff[4];
#pragma unroll
    for (int t = 0; t < 4; ++t) {
        aoff[t] = phys4(wm * 64 + t * 16 + mh, quad) * 8;
        boff[t] = phys4(wn * 64 + t * 16 + mh, quad) * 8;
    }

    for (int kt = 0; kt < 32; ++kt) {
        __syncthreads();
        async16(aptr[0], Atile + (w * 2 + 0) * 512);
        async16(aptr[1], Atile + (w * 2 + 1) * 512);
        async16(bptr[0], Btile + (w * 2 + 0) * 512);
        async16(bptr[1], Btile + (w * 2 + 1) * 512);
        aptr[0] += 32; aptr[1] += 32; bptr[0] += 32; bptr[1] += 32;
        __syncthreads();

        f16x8 af[4], bf[4];
#pragma unroll
        for (int t = 0; t < 4; ++t) af[t] = *(const f16x8*)(Atile + aoff[t]);
#pragma unroll
        for (int t = 0; t < 4; ++t) bf[t] = *(const f16x8*)(Btile + boff[t]);
#pragma unroll
        for (int i = 0; i < 4; ++i)
#pragma unroll
            for (int j = 0; j < 4; ++j)
                acc[i][j] = __builtin_amdgcn_mfma_f32_16x16x32_f16(
                    af[i], bf[j], acc[i][j], 0, 0, 0);
    }

    // epilogue: C row = quad*4+reg, col = mh (m89-verified layout)
    if (z < 2) {
        f16* outp = (z == 0) ? q16 : k16;
#pragma unroll
        for (int nt = 0; nt < 4; ++nt) {
            const int n = n0 + wn * 64 + nt * 16 + mh;
            const int h = n >> 6, d = n & 63;
            const float bn = bias[n];
#pragma unroll
            for (int mt = 0; mt < 4; ++mt) {
#pragma unroll
                for (int r = 0; r < 4; ++r) {
                    int m = m0 + wm * 64 + mt * 16 + quad * 4 + r;
                    int bbb = m >> 10, s = m & 1023;
                    outp[(((size_t)(bbb * kNH + h) * kS + s) << 6) + d] =
                        (f16)(acc[mt][nt][r] + bn);
                }
            }
        }
    } else {
#pragma unroll
        for (int nt = 0; nt < 4; ++nt) {
            const int n = n0 + wn * 64 + nt * 16 + mh;
            const int h = n >> 6, d = n & 63;
            const float bn = bias[n];
#pragma unroll
            for (int mt = 0; mt < 4; ++mt) {
                int mbase = m0 + wm * 64 + mt * 16 + quad * 4;
                int bbb = mbase >> 10, s0 = mbase & 1023;
                union { f16 h4[4]; uint2 u; } pk;
#pragma unroll
                for (int r = 0; r < 4; ++r) pk.h4[r] = (f16)(acc[mt][nt][r] + bn);
                *(uint2*)(vt + ((size_t)(bbb * kNH + h) * kHD + d) * kS + s0) = pk.u;
            }
        }
    }
}

// ---------------------------------------------------------------------------
// Context gating (f16 q/k in place, fp32 math). Grid-stride over rows.
// ---------------------------------------------------------------------------
__global__ __launch_bounds__(256) void gate_f16(
    const float* __restrict__ ce_full,
    const float* __restrict__ Wcq, const float* __restrict__ bcq,
    const float* __restrict__ Wck, const float* __restrict__ bck,
    const float* __restrict__ wlqc, const float* __restrict__ wlqq,
    const float* __restrict__ wlkc, const float* __restrict__ wlkk,
    f16* __restrict__ q16, f16* __restrict__ k16)
{
    const int gate = blockIdx.x >> 10;
    const int blk  = blockIdx.x & 1023;
    const float* Wc  = gate ? Wck  : Wcq;
    const float* bc  = gate ? bck  : bcq;
    const float* wlc = gate ? wlkc : wlqc;
    const float* wlx = gate ? wlkk : wlqq;
    f16* xw          = gate ? k16  : q16;

    __shared__ float Wls[kHD * kHD];
    for (int i = threadIdx.x; i < kHD * kHD; i += 256) Wls[i] = Wc[i];
    __syncthreads();

    const int wv = threadIdx.x >> 6, lane = threadIdx.x & 63;
    const float bcl = bc[lane], wlcl = wlc[lane], wlxl = wlx[lane];

    for (int rr = wv; rr < 128; rr += 4) {
        const int row = blk * 128 + rr;
        const int s = row & 1023, bh = row >> 10;
        const int h = bh & 15, bbb = bh >> 4;

        const float cev = ce_full[((size_t)(bbb * kS + s)) * kH + (h << 6) + lane];
        const float x   = (float)xw[(size_t)row * kHD + lane];

        float ceq = bcl;
#pragma unroll
        for (int e = 0; e < kHD; ++e)
            ceq += __shfl(cev, e, 64) * Wls[e * kHD + lane];

        float t = ceq * wlcl + x * wlxl;
#pragma unroll
        for (int off = 32; off > 0; off >>= 1) t += __shfl_xor(t, off, 64);
        const float lam = 1.0f / (1.0f + __expf(-t));

        xw[(size_t)row * kHD + lane] = (f16)((1.0f - lam) * x + lam * ceq);
    }
}

// ---------------------------------------------------------------------------
// MFMA flash attention. Block=4 waves, 64 Q-rows (16/wave), K-tiles of 64.
// Q-frags hoisted to regs; K/V^T staged via swizzled global_load_lds;
// online softmax in C-layout; P via padded per-wave LDS (C->A layout).
// ---------------------------------------------------------------------------
__global__ __launch_bounds__(256) void attn_f16(
    const f16* __restrict__ q16, const f16* __restrict__ k16,
    const f16* __restrict__ vt, const float* __restrict__ mask,
    float* __restrict__ out)
{
    __shared__ f16 Qs[64 * 64];
    __shared__ f16 Ks[64 * 64];
    __shared__ f16 Vs[64 * 64];
    __shared__ f16 Ps[4][16 * 72];   // per-wave, rows padded to 72 f16 (144B)

    const int tid = threadIdx.x;
    const int w = tid >> 6, lane = tid & 63;
    const int quad = lane >> 4, mh = lane & 15;
    const int bh = blockIdx.y, bbb = bh >> 4, h = bh & 15;
    const int q0 = blockIdx.x * 64;
    const float* maskb = mask + bbb * kS;

    // swizzle-inverted staging coords, 2 issues/wave (shared by Q/K/V geometry)
    int mS[2], cS[2];
#pragma unroll
    for (int i = 0; i < 2; ++i) {
        int P = (w * 2 + i) * 64 + lane;
        mS[i] = P >> 3;
        cS[i] = (P & 7) ^ (mS[i] & 7);
    }

    // stage Q once
#pragma unroll
    for (int i = 0; i < 2; ++i)
        async16(q16 + ((size_t)bh * kS + q0 + mS[i]) * kHD + cS[i] * 8,
                Qs + (w * 2 + i) * 512);
    __syncthreads();

    f16x8 qf[2];
#pragma unroll
    for (int ks = 0; ks < 2; ++ks)
        qf[ks] = *(const f16x8*)(Qs + phys8(w * 16 + mh, ks * 4 + quad) * 8);

    const f16* kp[2]; const f16* vp[2];
#pragma unroll
    for (int i = 0; i < 2; ++i) {
        kp[i] = k16 + ((size_t)bh * kS + mS[i]) * kHD + cS[i] * 8;
        vp[i] = vt  + ((size_t)bh * kHD + mS[i]) * kS + cS[i] * 8;
    }

    f32x4 O[4];
#pragma unroll
    for (int i = 0; i < 4; ++i) O[i] = (f32x4){0.f, 0.f, 0.f, 0.f};
    float m_i[4] = {-1e30f, -1e30f, -1e30f, -1e30f};
    float l_i[4] = {0.f, 0.f, 0.f, 0.f};

    for (int jt = 0; jt < kS; jt += 64) {
        __syncthreads();
#pragma unroll
        for (int i = 0; i < 2; ++i) {
            async16(kp[i], Ks + (w * 2 + i) * 512);
            async16(vp[i], Vs + (w * 2 + i) * 512);
            kp[i] += 64 * kHD;   // next 64 key rows
            vp[i] += 64;         // next 64 key cols
        }
        __syncthreads();

        // S = Q K^T (C-layout: row=quad*4+r, col=nt*16+mh)
        f32x4 S[4];
#pragma unroll
        for (int nt = 0; nt < 4; ++nt) {
            f16x8 kf0 = *(const f16x8*)(Ks + phys8(nt * 16 + mh, 0 + quad) * 8);
            f16x8 kf1 = *(const f16x8*)(Ks + phys8(nt * 16 + mh, 4 + quad) * 8);
            S[nt] = __builtin_amdgcn_mfma_f32_16x16x32_f16(
                qf[0], kf0, (f32x4){0.f, 0.f, 0.f, 0.f}, 0, 0, 0);
            S[nt] = __builtin_amdgcn_mfma_f32_16x16x32_f16(qf[1], kf1, S[nt], 0, 0, 0);
        }

        // scale + mask
#pragma unroll
        for (int nt = 0; nt < 4; ++nt) {
            const float mv = maskb[jt + nt * 16 + mh];
#pragma unroll
            for (int r = 0; r < 4; ++r) S[nt][r] = S[nt][r] * 0.125f + mv;
        }

        // online softmax (row stats across the 16-lane col group)
        float alpha[4];
#pragma unroll
        for (int r = 0; r < 4; ++r) {
            float mx = fmaxf(fmaxf(S[0][r], S[1][r]), fmaxf(S[2][r], S[3][r]));
#pragma unroll
            for (int off = 1; off < 16; off <<= 1)
                mx = fmaxf(mx, __shfl_xor(mx, off, 64));
            const float mn = fmaxf(m_i[r], mx);
            alpha[r] = __expf(m_i[r] - mn);
            float rs = 0.f;
#pragma unroll
            for (int nt = 0; nt < 4; ++nt) {
                S[nt][r] = __expf(S[nt][r] - mn);
                rs += S[nt][r];
            }
#pragma unroll
            for (int off = 1; off < 16; off <<= 1)
                rs += __shfl_xor(rs, off, 64);
            l_i[r] = l_i[r] * alpha[r] + rs;
            m_i[r] = mn;
        }
#pragma unroll
        for (int dt = 0; dt < 4; ++dt)
#pragma unroll
            for (int r = 0; r < 4; ++r) O[dt][r] *= alpha[r];

        // P: C-layout -> per-wave LDS [16 q-rows][64 keys] (padded 72)
#pragma unroll
        for (int nt = 0; nt < 4; ++nt)
#pragma unroll
            for (int r = 0; r < 4; ++r)
                Ps[w][(quad * 4 + r) * 72 + nt * 16 + mh] = (f16)S[nt][r];

        f16x8 pf[2];
#pragma unroll
        for (int ks = 0; ks < 2; ++ks)
            pf[ks] = *(const f16x8*)(&Ps[w][mh * 72 + ks * 32 + quad * 8]);

        // O += P V
#pragma unroll
        for (int dt = 0; dt < 4; ++dt) {
            f16x8 vf0 = *(const f16x8*)(Vs + phys8(dt * 16 + mh, 0 + quad) * 8);
            f16x8 vf1 = *(const f16x8*)(Vs + phys8(dt * 16 + mh, 4 + quad) * 8);
            O[dt] = __builtin_amdgcn_mfma_f32_16x16x32_f16(pf[0], vf0, O[dt], 0, 0, 0);
            O[dt] = __builtin_amdgcn_mfma_f32_16x16x32_f16(pf[1], vf1, O[dt], 0, 0, 0);
        }
    }

    // epilogue: O /= l, write [B,S,H]
#pragma unroll
    for (int dt = 0; dt < 4; ++dt) {
#pragma unroll
        for (int r = 0; r < 4; ++r) {
            const int s = q0 + w * 16 + quad * 4 + r;
            out[((size_t)(bbb * kS + s)) * kH + (h << 6) + dt * 16 + mh] =
                O[dt][r] / l_i[r];
        }
    }
}

// ---------------------------------------------------------------------------
extern "C" void kernel_launch(void* const* d_in, const int* in_sizes, int n_in,
                              void* d_out, int out_size, void* d_ws, size_t ws_size,
                              hipStream_t stream) {
    (void)in_sizes; (void)n_in; (void)out_size; (void)ws_size;

    const float* hs   = (const float*)d_in[0];
    const float* mask = (const float*)d_in[1];
    const float* ce   = (const float*)d_in[2];
    const float* Wq   = (const float*)d_in[3];
    const float* bq   = (const float*)d_in[4];
    const float* Wk   = (const float*)d_in[5];
    const float* bk   = (const float*)d_in[6];
    const float* Wv   = (const float*)d_in[7];
    const float* bv   = (const float*)d_in[8];
    const float* Wcq  = (const float*)d_in[9];
    const float* bcq  = (const float*)d_in[10];
    const float* Wck  = (const float*)d_in[11];
    const float* bck  = (const float*)d_in[12];
    const float* wlqc = (const float*)d_in[13];
    const float* wlqq = (const float*)d_in[14];
    const float* wlkc = (const float*)d_in[15];
    const float* wlkk = (const float*)d_in[16];
    float* out = (float*)d_out;

    f16* hs16 = (f16*)d_ws;                            // 16.78 MB
    f16* Wt   = hs16 + (size_t)kB * kS * kH;           // 6.29 MB (3 weights, B^T)
    f16* q16  = Wt + (size_t)3 * kH * kH;              // 16.78 MB
    f16* k16  = q16 + (size_t)kRows * kHD;             // 16.78 MB
    f16* vt   = k16 + (size_t)kRows * kHD;             // 16.78 MB  [bh][d][s]

    cast_hs_kernel<<<dim3(kB * kS * kH / (256 * 8)), 256, 0, stream>>>(hs, hs16);
    transpose_w_kernel<<<dim3(16, 16, 3), 256, 0, stream>>>(Wq, Wk, Wv, Wt);

    qkv_gemm_f16<<<dim3(kH / 128, kB * kS / 128, 3), 256, 0, stream>>>(
        hs16, Wt, bq, bk, bv, q16, k16, vt);

    gate_f16<<<dim3(2048), 256, 0, stream>>>(
        ce, Wcq, bcq, Wck, bck, wlqc, wlqq, wlkc, wlkk, q16, k16);

    attn_f16<<<dim3(kS / 64, kBH), 256, 0, stream>>>(q16, k16, vt, mask, out);
}

// Round 3
// 364.355 us; speedup vs baseline: 4.0996x; 1.4390x over previous
//
#include <hip/hip_runtime.h>

typedef _Float16 f16;
typedef f16   f16x8 __attribute__((ext_vector_type(8)));
typedef float f32x4 __attribute__((ext_vector_type(4)));

namespace {
constexpr int kB  = 8;
constexpr int kS  = 1024;
constexpr int kH  = 1024;
constexpr int kNH = 16;
constexpr int kHD = 64;
constexpr int kBH = kB * kNH;            // 128
constexpr int kRows = kBH * kS;          // 131072
}

// async global->LDS, 16B per lane; LDS dest = wave-uniform base + lane*16
__device__ __forceinline__ void async16(const f16* g, f16* l) {
    __builtin_amdgcn_global_load_lds(
        (const __attribute__((address_space(1))) unsigned int*)g,
        (__attribute__((address_space(3))) unsigned int*)l, 16, 0, 0);
}

// --- LDS chunk swizzles (16B chunks). Uniform bank-slot histogram per quad
// for MFMA fragment reads; invertible for global_load_lds staging. ---
// 64B rows (4 chunks/row), paired rows share a 128B bank group:
__device__ __forceinline__ int phys4(int m, int c) {
    return ((m >> 1) << 3) | ((((m & 1) << 2) | c) ^ ((m >> 1) & 7));
}
// 128B rows (8 chunks/row):
__device__ __forceinline__ int phys8(int m, int c) {
    return (m << 3) | (c ^ (m & 7));
}

// ---------------------------------------------------------------------------
// Cast hs fp32 -> f16 (flat)
// ---------------------------------------------------------------------------
__global__ __launch_bounds__(256) void cast_hs_kernel(
    const float* __restrict__ hs, f16* __restrict__ out)
{
    int i = (blockIdx.x * 256 + threadIdx.x) * 8;
    float4 a = *(const float4*)(hs + i);
    float4 b = *(const float4*)(hs + i + 4);
    union { f16 h[8]; uint4 u; } pk;
    pk.h[0] = (f16)a.x; pk.h[1] = (f16)a.y; pk.h[2] = (f16)a.z; pk.h[3] = (f16)a.w;
    pk.h[4] = (f16)b.x; pk.h[5] = (f16)b.y; pk.h[6] = (f16)b.z; pk.h[7] = (f16)b.w;
    *(uint4*)(out + i) = pk.u;
}

// ---------------------------------------------------------------------------
// Cast ce fp32 [B,S,H] -> f16 head-split [bh][s][d]
// ---------------------------------------------------------------------------
__global__ __launch_bounds__(256) void cast_ce_kernel(
    const float* __restrict__ ce, f16* __restrict__ out)
{
    int i = (blockIdx.x * 256 + threadIdx.x) * 8;
    float4 a = *(const float4*)(ce + i);
    float4 b = *(const float4*)(ce + i + 4);
    union { f16 h[8]; uint4 u; } pk;
    pk.h[0] = (f16)a.x; pk.h[1] = (f16)a.y; pk.h[2] = (f16)a.z; pk.h[3] = (f16)a.w;
    pk.h[4] = (f16)b.x; pk.h[5] = (f16)b.y; pk.h[6] = (f16)b.z; pk.h[7] = (f16)b.w;
    int row = i >> 10, col = i & 1023;           // row = b*1024+s
    int bb = row >> 10, s = row & 1023;
    int h = col >> 6, d = col & 63;
    size_t o = ((((size_t)(bb * kNH + h) << 10) | s) << 6) | d;
    *(uint4*)(out + o) = pk.u;
}

// ---------------------------------------------------------------------------
// Transpose+cast W [K][N] fp32 -> Wt [N][K] f16 (B^T layout for the GEMM)
// ---------------------------------------------------------------------------
__global__ __launch_bounds__(256) void transpose_w_kernel(
    const float* __restrict__ Wq, const float* __restrict__ Wk,
    const float* __restrict__ Wv, f16* __restrict__ Wt)
{
    const float* W = (blockIdx.z == 0) ? Wq : (blockIdx.z == 1) ? Wk : Wv;
    f16* out = Wt + (size_t)blockIdx.z * kH * kH;
    __shared__ f16 T[64][72];
    const int tid = threadIdx.x;
    const int k0 = blockIdx.y * 64, n0 = blockIdx.x * 64;
#pragma unroll
    for (int i = 0; i < 4; ++i) {
        int idx = tid + i * 256;
        int r = idx >> 4, cb = (idx & 15) * 4;
        float4 v = *(const float4*)(W + (size_t)(k0 + r) * kH + n0 + cb);
        T[cb + 0][r] = (f16)v.x; T[cb + 1][r] = (f16)v.y;
        T[cb + 2][r] = (f16)v.z; T[cb + 3][r] = (f16)v.w;
    }
    __syncthreads();
#pragma unroll
    for (int i = 0; i < 4; ++i) {
        int idx = tid + i * 256;
        int r = idx >> 4, cb = (idx & 15) * 4;
        union { f16 h[4]; uint2 u; } pk;
#pragma unroll
        for (int j = 0; j < 4; ++j) pk.h[j] = T[r][cb + j];
        *(uint2*)(out + (size_t)(n0 + r) * kH + k0 + cb) = pk.u;
    }
}

// ---------------------------------------------------------------------------
// Transpose+cast Wcq/Wck [64k][64n] fp32 -> f16 [n][k] (tiny, 2 blocks)
// ---------------------------------------------------------------------------
__global__ __launch_bounds__(256) void transpose_wc_kernel(
    const float* __restrict__ Wcq, const float* __restrict__ Wck,
    f16* __restrict__ Wct)
{
    const float* W = blockIdx.x ? Wck : Wcq;
    f16* out = Wct + blockIdx.x * kHD * kHD;
    const int t = threadIdx.x;
#pragma unroll
    for (int i = 0; i < 16; ++i) {
        int idx = i * 256 + t;
        int k = idx >> 6, n = idx & 63;
        out[n * 64 + k] = (f16)W[idx];
    }
}

// ---------------------------------------------------------------------------
// QKV GEMM, f16 MFMA (m97 structure). C = hs16 @ W (+bias).
// 128x128 tile, BK=32, 4 waves each 64x64 (4x4 tiles of 16x16x32).
// q/k written f16 head-split [bh][s][d]; V written TRANSPOSED f16 [bh][d][s].
// ---------------------------------------------------------------------------
__global__ __launch_bounds__(256) void qkv_gemm_f16(
    const f16* __restrict__ hs16, const f16* __restrict__ Wt,
    const float* __restrict__ bq, const float* __restrict__ bk,
    const float* __restrict__ bv,
    f16* __restrict__ q16, f16* __restrict__ k16, f16* __restrict__ vt)
{
    const int z = blockIdx.z;
    const f16* Bmat = Wt + (size_t)z * kH * kH;
    const float* bias = (z == 0) ? bq : (z == 1) ? bk : bv;

    __shared__ f16 Atile[128 * 32];
    __shared__ f16 Btile[128 * 32];

    const int tid = threadIdx.x;
    const int w = tid >> 6, lane = tid & 63;
    const int quad = lane >> 4, mh = lane & 15;
    const int wm = w >> 1, wn = w & 1;
    const int m0 = blockIdx.y * 128, n0 = blockIdx.x * 128;

    const f16* aptr[2]; const f16* bptr[2];
#pragma unroll
    for (int i = 0; i < 2; ++i) {
        int P = (w * 2 + i) * 64 + lane;
        int r2 = P >> 3, s = P & 7;
        int bb = s ^ (r2 & 7);
        int m = (r2 << 1) | (bb >> 2), c = bb & 3;
        aptr[i] = hs16 + (size_t)(m0 + m) * kH + c * 8;
        bptr[i] = Bmat + (size_t)(n0 + m) * kH + c * 8;
    }

    f32x4 acc[4][4];
#pragma unroll
    for (int i = 0; i < 4; ++i)
#pragma unroll
        for (int j = 0; j < 4; ++j) acc[i][j] = (f32x4){0.f, 0.f, 0.f, 0.f};

    int aoff[4], boff[4];
#pragma unroll
    for (int t = 0; t < 4; ++t) {
        aoff[t] = phys4(wm * 64 + t * 16 + mh, quad) * 8;
        boff[t] = phys4(wn * 64 + t * 16 + mh, quad) * 8;
    }

    for (int kt = 0; kt < 32; ++kt) {
        __syncthreads();
        async16(aptr[0], Atile + (w * 2 + 0) * 512);
        async16(aptr[1], Atile + (w * 2 + 1) * 512);
        async16(bptr[0], Btile + (w * 2 + 0) * 512);
        async16(bptr[1], Btile + (w * 2 + 1) * 512);
        aptr[0] += 32; aptr[1] += 32; bptr[0] += 32; bptr[1] += 32;
        __syncthreads();

        f16x8 af[4], bf[4];
#pragma unroll
        for (int t = 0; t < 4; ++t) af[t] = *(const f16x8*)(Atile + aoff[t]);
#pragma unroll
        for (int t = 0; t < 4; ++t) bf[t] = *(const f16x8*)(Btile + boff[t]);
#pragma unroll
        for (int i = 0; i < 4; ++i)
#pragma unroll
            for (int j = 0; j < 4; ++j)
                acc[i][j] = __builtin_amdgcn_mfma_f32_16x16x32_f16(
                    af[i], bf[j], acc[i][j], 0, 0, 0);
    }

    if (z < 2) {
        f16* outp = (z == 0) ? q16 : k16;
#pragma unroll
        for (int nt = 0; nt < 4; ++nt) {
            const int n = n0 + wn * 64 + nt * 16 + mh;
            const int h = n >> 6, d = n & 63;
            const float bn = bias[n];
#pragma unroll
            for (int mt = 0; mt < 4; ++mt) {
#pragma unroll
                for (int r = 0; r < 4; ++r) {
                    int m = m0 + wm * 64 + mt * 16 + quad * 4 + r;
                    int bbb = m >> 10, s = m & 1023;
                    outp[(((size_t)(bbb * kNH + h) * kS + s) << 6) + d] =
                        (f16)(acc[mt][nt][r] + bn);
                }
            }
        }
    } else {
#pragma unroll
        for (int nt = 0; nt < 4; ++nt) {
            const int n = n0 + wn * 64 + nt * 16 + mh;
            const int h = n >> 6, d = n & 63;
            const float bn = bias[n];
#pragma unroll
            for (int mt = 0; mt < 4; ++mt) {
                int mbase = m0 + wm * 64 + mt * 16 + quad * 4;
                int bbb = mbase >> 10, s0 = mbase & 1023;
                union { f16 h4[4]; uint2 u; } pk;
#pragma unroll
                for (int r = 0; r < 4; ++r) pk.h4[r] = (f16)(acc[mt][nt][r] + bn);
                *(uint2*)(vt + ((size_t)(bbb * kNH + h) * kHD + d) * kS + s0) = pk.u;
            }
        }
    }
}

// ---------------------------------------------------------------------------
// Context gating, MFMA version. One wave per 64-row tile.
// ce_q = ce@Wc + bc (MFMA); t = ce_q.wlc + x.wlx (C-layout partials + LDS
// scratch reduce); lam = sigmoid(t); x = (1-lam)x + lam*ce_q (coalesced).
// ---------------------------------------------------------------------------
__global__ __launch_bounds__(256) void gate_mfma(
    const f16* __restrict__ ce16, const f16* __restrict__ Wct,
    const float* __restrict__ bcq, const float* __restrict__ bck,
    const float* __restrict__ wlqc, const float* __restrict__ wlqq,
    const float* __restrict__ wlkc, const float* __restrict__ wlkk,
    f16* __restrict__ q16, f16* __restrict__ k16)
{
    __shared__ f16 Wls[64 * 64];          // swizzled [n][k]
    __shared__ f16 CeQ[4][64 * 64];       // per wave: ce tile, then ceq out
    __shared__ float Tp[4][64 * 17];      // per wave: t partials (+xdot col 16)
    __shared__ float lamS[4][64];

    const int tid = threadIdx.x, w = tid >> 6, lane = tid & 63;
    const int quad = lane >> 4, mh = lane & 15;
    const int gate = blockIdx.x >> 9;
    const int tIdx = (blockIdx.x & 511) * 4 + w;
    const size_t row0 = (size_t)tIdx * 64;     // 64-row tile, within one bh

    const float* bc  = gate ? bck  : bcq;
    const float* wlc = gate ? wlkc : wlqc;
    const float* wlx = gate ? wlkk : wlqq;
    f16* xw = (gate ? k16 : q16) + row0 * kHD;
    const f16* cep = ce16 + row0 * kHD;
    const f16* Wcg = Wct + gate * kHD * kHD;

    // stage Wc block-wide (512 chunks / 256 threads), swizzled
#pragma unroll
    for (int i = 0; i < 2; ++i) {
        int P = tid + i * 256;
        int m = P >> 3, c = P & 7;
        *(uint4*)(Wls + phys8(m, c) * 8) = *(const uint4*)(Wcg + m * 64 + c * 8);
    }
    // stage ce tile per wave: 8 async16 issues (swizzle-inverted source)
#pragma unroll
    for (int i = 0; i < 8; ++i) {
        int P = i * 64 + lane;
        int m = P >> 3, c = (P & 7) ^ (m & 7);
        async16(cep + m * 64 + c * 8, CeQ[w] + i * 512);
    }
    __syncthreads();

    // xdot pass: t_x[row] = x[row,:].wlx  (coalesced 16B/lane global reads)
#pragma unroll
    for (int it = 0; it < 8; ++it) {
        int slot = it * 64 + lane;
        int r = slot >> 3, c = slot & 7;
        union { uint4 u; f16 h[8]; } xv;
        xv.u = *(const uint4*)(xw + r * 64 + c * 8);
        float4 wa = ((const float4*)wlx)[c * 2];
        float4 wb = ((const float4*)wlx)[c * 2 + 1];
        float s = (float)xv.h[0] * wa.x + (float)xv.h[1] * wa.y +
                  (float)xv.h[2] * wa.z + (float)xv.h[3] * wa.w +
                  (float)xv.h[4] * wb.x + (float)xv.h[5] * wb.y +
                  (float)xv.h[6] * wb.z + (float)xv.h[7] * wb.w;
        s += __shfl_xor(s, 1, 64);
        s += __shfl_xor(s, 2, 64);
        s += __shfl_xor(s, 4, 64);
        if ((lane & 7) == 0) Tp[w][r * 17 + 16] = s;
    }

    // MFMA: ceq = ce @ Wc
    f32x4 acc[4][4];
#pragma unroll
    for (int i = 0; i < 4; ++i)
#pragma unroll
        for (int j = 0; j < 4; ++j) acc[i][j] = (f32x4){0.f, 0.f, 0.f, 0.f};

    f16x8 bfr[4][2];
#pragma unroll
    for (int nt = 0; nt < 4; ++nt)
#pragma unroll
        for (int ks = 0; ks < 2; ++ks)
            bfr[nt][ks] = *(const f16x8*)(Wls + phys8(nt * 16 + mh, ks * 4 + quad) * 8);
#pragma unroll
    for (int mt = 0; mt < 4; ++mt) {
        f16x8 a0 = *(const f16x8*)(CeQ[w] + phys8(mt * 16 + mh, 0 + quad) * 8);
        f16x8 a1 = *(const f16x8*)(CeQ[w] + phys8(mt * 16 + mh, 4 + quad) * 8);
#pragma unroll
        for (int nt = 0; nt < 4; ++nt) {
            acc[mt][nt] = __builtin_amdgcn_mfma_f32_16x16x32_f16(a0, bfr[nt][0], acc[mt][nt], 0, 0, 0);
            acc[mt][nt] = __builtin_amdgcn_mfma_f32_16x16x32_f16(a1, bfr[nt][1], acc[mt][nt], 0, 0, 0);
        }
    }

    // epilogue: +bias, store ceq (f16, aliased over ce tile — A-frag reads
    // are already register-consumed), accumulate t partials
    float bcv[4], wlcv[4];
#pragma unroll
    for (int nt = 0; nt < 4; ++nt) {
        int n = nt * 16 + mh;
        bcv[nt] = bc[n]; wlcv[nt] = wlc[n];
    }
#pragma unroll
    for (int mt = 0; mt < 4; ++mt) {
#pragma unroll
        for (int r = 0; r < 4; ++r) {
            int m = mt * 16 + quad * 4 + r;
            float tpv = 0.f;
#pragma unroll
            for (int nt = 0; nt < 4; ++nt) {
                float v = acc[mt][nt][r] + bcv[nt];
                int col = nt * 16 + mh;
                CeQ[w][phys8(m, col >> 3) * 8 + (col & 7)] = (f16)v;
                tpv += v * wlcv[nt];
            }
            Tp[w][m * 17 + mh] = tpv;
        }
    }

    // per-row reduce (same-wave DS ops are pipe-ordered) + sigmoid
    float t = 0.f;
#pragma unroll
    for (int j = 0; j < 17; ++j) t += Tp[w][lane * 17 + j];
    lamS[w][lane] = 1.0f / (1.0f + __expf(-t));

    // blend pass: x = (1-lam)x + lam*ceq, coalesced 16B/lane
#pragma unroll
    for (int it = 0; it < 8; ++it) {
        int slot = it * 64 + lane;
        int r = slot >> 3, c = slot & 7;
        float lam = lamS[w][r];
        union { uint4 u; f16 h[8]; } xv;
        xv.u = *(const uint4*)(xw + r * 64 + c * 8);
        f16x8 cq = *(const f16x8*)(CeQ[w] + phys8(r, c) * 8);
        union { f16 h[8]; uint4 u; } o;
#pragma unroll
        for (int j = 0; j < 8; ++j)
            o.h[j] = (f16)((1.0f - lam) * (float)xv.h[j] + lam * (float)cq[j]);
        *(uint4*)(xw + r * 64 + c * 8) = o.u;
    }
}

// ---------------------------------------------------------------------------
// MFMA flash attention. Block=4 waves, 64 Q-rows (16/wave), K-tiles of 64.
// ---------------------------------------------------------------------------
__global__ __launch_bounds__(256) void attn_f16(
    const f16* __restrict__ q16, const f16* __restrict__ k16,
    const f16* __restrict__ vt, const float* __restrict__ mask,
    float* __restrict__ out)
{
    __shared__ f16 Qs[64 * 64];
    __shared__ f16 Ks[64 * 64];
    __shared__ f16 Vs[64 * 64];
    __shared__ f16 Ps[4][16 * 72];

    const int tid = threadIdx.x;
    const int w = tid >> 6, lane = tid & 63;
    const int quad = lane >> 4, mh = lane & 15;
    const int bh = blockIdx.y, bbb = bh >> 4, h = bh & 15;
    const int q0 = blockIdx.x * 64;
    const float* maskb = mask + bbb * kS;

    int mS[2], cS[2];
#pragma unroll
    for (int i = 0; i < 2; ++i) {
        int P = (w * 2 + i) * 64 + lane;
        mS[i] = P >> 3;
        cS[i] = (P & 7) ^ (mS[i] & 7);
    }

#pragma unroll
    for (int i = 0; i < 2; ++i)
        async16(q16 + ((size_t)bh * kS + q0 + mS[i]) * kHD + cS[i] * 8,
                Qs + (w * 2 + i) * 512);
    __syncthreads();

    f16x8 qf[2];
#pragma unroll
    for (int ks = 0; ks < 2; ++ks)
        qf[ks] = *(const f16x8*)(Qs + phys8(w * 16 + mh, ks * 4 + quad) * 8);

    const f16* kp[2]; const f16* vp[2];
#pragma unroll
    for (int i = 0; i < 2; ++i) {
        kp[i] = k16 + ((size_t)bh * kS + mS[i]) * kHD + cS[i] * 8;
        vp[i] = vt  + ((size_t)bh * kHD + mS[i]) * kS + cS[i] * 8;
    }

    f32x4 O[4];
#pragma unroll
    for (int i = 0; i < 4; ++i) O[i] = (f32x4){0.f, 0.f, 0.f, 0.f};
    float m_i[4] = {-1e30f, -1e30f, -1e30f, -1e30f};
    float l_i[4] = {0.f, 0.f, 0.f, 0.f};

    for (int jt = 0; jt < kS; jt += 64) {
        __syncthreads();
#pragma unroll
        for (int i = 0; i < 2; ++i) {
            async16(kp[i], Ks + (w * 2 + i) * 512);
            async16(vp[i], Vs + (w * 2 + i) * 512);
            kp[i] += 64 * kHD;
            vp[i] += 64;
        }
        __syncthreads();

        f32x4 S[4];
#pragma unroll
        for (int nt = 0; nt < 4; ++nt) {
            f16x8 kf0 = *(const f16x8*)(Ks + phys8(nt * 16 + mh, 0 + quad) * 8);
            f16x8 kf1 = *(const f16x8*)(Ks + phys8(nt * 16 + mh, 4 + quad) * 8);
            S[nt] = __builtin_amdgcn_mfma_f32_16x16x32_f16(
                qf[0], kf0, (f32x4){0.f, 0.f, 0.f, 0.f}, 0, 0, 0);
            S[nt] = __builtin_amdgcn_mfma_f32_16x16x32_f16(qf[1], kf1, S[nt], 0, 0, 0);
        }

#pragma unroll
        for (int nt = 0; nt < 4; ++nt) {
            const float mv = maskb[jt + nt * 16 + mh];
#pragma unroll
            for (int r = 0; r < 4; ++r) S[nt][r] = S[nt][r] * 0.125f + mv;
        }

        float alpha[4];
#pragma unroll
        for (int r = 0; r < 4; ++r) {
            float mx = fmaxf(fmaxf(S[0][r], S[1][r]), fmaxf(S[2][r], S[3][r]));
#pragma unroll
            for (int off = 1; off < 16; off <<= 1)
                mx = fmaxf(mx, __shfl_xor(mx, off, 64));
            const float mn = fmaxf(m_i[r], mx);
            alpha[r] = __expf(m_i[r] - mn);
            float rs = 0.f;
#pragma unroll
            for (int nt = 0; nt < 4; ++nt) {
                S[nt][r] = __expf(S[nt][r] - mn);
                rs += S[nt][r];
            }
#pragma unroll
            for (int off = 1; off < 16; off <<= 1)
                rs += __shfl_xor(rs, off, 64);
            l_i[r] = l_i[r] * alpha[r] + rs;
            m_i[r] = mn;
        }
#pragma unroll
        for (int dt = 0; dt < 4; ++dt)
#pragma unroll
            for (int r = 0; r < 4; ++r) O[dt][r] *= alpha[r];

#pragma unroll
        for (int nt = 0; nt < 4; ++nt)
#pragma unroll
            for (int r = 0; r < 4; ++r)
                Ps[w][(quad * 4 + r) * 72 + nt * 16 + mh] = (f16)S[nt][r];

        f16x8 pf[2];
#pragma unroll
        for (int ks = 0; ks < 2; ++ks)
            pf[ks] = *(const f16x8*)(&Ps[w][mh * 72 + ks * 32 + quad * 8]);

#pragma unroll
        for (int dt = 0; dt < 4; ++dt) {
            f16x8 vf0 = *(const f16x8*)(Vs + phys8(dt * 16 + mh, 0 + quad) * 8);
            f16x8 vf1 = *(const f16x8*)(Vs + phys8(dt * 16 + mh, 4 + quad) * 8);
            O[dt] = __builtin_amdgcn_mfma_f32_16x16x32_f16(pf[0], vf0, O[dt], 0, 0, 0);
            O[dt] = __builtin_amdgcn_mfma_f32_16x16x32_f16(pf[1], vf1, O[dt], 0, 0, 0);
        }
    }

#pragma unroll
    for (int dt = 0; dt < 4; ++dt) {
#pragma unroll
        for (int r = 0; r < 4; ++r) {
            const int s = q0 + w * 16 + quad * 4 + r;
            out[((size_t)(bbb * kS + s)) * kH + (h << 6) + dt * 16 + mh] =
                O[dt][r] / l_i[r];
        }
    }
}

// ---------------------------------------------------------------------------
extern "C" void kernel_launch(void* const* d_in, const int* in_sizes, int n_in,
                              void* d_out, int out_size, void* d_ws, size_t ws_size,
                              hipStream_t stream) {
    (void)in_sizes; (void)n_in; (void)out_size; (void)ws_size;

    const float* hs   = (const float*)d_in[0];
    const float* mask = (const float*)d_in[1];
    const float* ce   = (const float*)d_in[2];
    const float* Wq   = (const float*)d_in[3];
    const float* bq   = (const float*)d_in[4];
    const float* Wk   = (const float*)d_in[5];
    const float* bk   = (const float*)d_in[6];
    const float* Wv   = (const float*)d_in[7];
    const float* bv   = (const float*)d_in[8];
    const float* Wcq  = (const float*)d_in[9];
    const float* bcq  = (const float*)d_in[10];
    const float* Wck  = (const float*)d_in[11];
    const float* bck  = (const float*)d_in[12];
    const float* wlqc = (const float*)d_in[13];
    const float* wlqq = (const float*)d_in[14];
    const float* wlkc = (const float*)d_in[15];
    const float* wlkk = (const float*)d_in[16];
    float* out = (float*)d_out;

    f16* hs16 = (f16*)d_ws;                            // 16.78 MB
    f16* Wt   = hs16 + (size_t)kB * kS * kH;           // 6.29 MB
    f16* q16  = Wt + (size_t)3 * kH * kH;              // 16.78 MB
    f16* k16  = q16 + (size_t)kRows * kHD;             // 16.78 MB
    f16* vt   = k16 + (size_t)kRows * kHD;             // 16.78 MB  [bh][d][s]
    f16* ce16 = vt + (size_t)kRows * kHD;              // 16.78 MB  [bh][s][d]
    f16* Wct  = ce16 + (size_t)kRows * kHD;            // 16 KB (2x 64x64, [n][k])

    cast_hs_kernel<<<dim3(kB * kS * kH / (256 * 8)), 256, 0, stream>>>(hs, hs16);
    cast_ce_kernel<<<dim3(kB * kS * kH / (256 * 8)), 256, 0, stream>>>(ce, ce16);
    transpose_w_kernel<<<dim3(16, 16, 3), 256, 0, stream>>>(Wq, Wk, Wv, Wt);
    transpose_wc_kernel<<<dim3(2), 256, 0, stream>>>(Wcq, Wck, Wct);

    qkv_gemm_f16<<<dim3(kH / 128, kB * kS / 128, 3), 256, 0, stream>>>(
        hs16, Wt, bq, bk, bv, q16, k16, vt);

    gate_mfma<<<dim3(1024), 256, 0, stream>>>(
        ce16, Wct, bcq, bck, wlqc, wlqq, wlkc, wlkk, q16, k16);

    attn_f16<<<dim3(kS / 64, kBH), 256, 0, stream>>>(q16, k16, vt, mask, out);
}

// Round 4
// 342.073 us; speedup vs baseline: 4.3667x; 1.0651x over previous
//
#include <hip/hip_runtime.h>

typedef _Float16 f16;
typedef f16   f16x8 __attribute__((ext_vector_type(8)));
typedef float f32x4 __attribute__((ext_vector_type(4)));

namespace {
constexpr int kB  = 8;
constexpr int kS  = 1024;
constexpr int kH  = 1024;
constexpr int kNH = 16;
constexpr int kHD = 64;
constexpr int kBH = kB * kNH;            // 128
constexpr int kRows = kBH * kS;          // 131072
}

// async global->LDS, 16B per lane; LDS dest = wave-uniform base + lane*16
__device__ __forceinline__ void async16(const f16* g, f16* l) {
    __builtin_amdgcn_global_load_lds(
        (const __attribute__((address_space(1))) unsigned int*)g,
        (__attribute__((address_space(3))) unsigned int*)l, 16, 0, 0);
}

// --- LDS chunk swizzles (16B chunks). Uniform bank-slot histogram per quad
// for MFMA fragment reads; invertible for global_load_lds staging. ---
__device__ __forceinline__ int phys4(int m, int c) {
    return ((m >> 1) << 3) | ((((m & 1) << 2) | c) ^ ((m >> 1) & 7));
}
__device__ __forceinline__ int phys8(int m, int c) {
    return (m << 3) | (c ^ (m & 7));
}

// ---------------------------------------------------------------------------
// Cast hs fp32 -> f16 (flat)
// ---------------------------------------------------------------------------
__global__ __launch_bounds__(256) void cast_hs_kernel(
    const float* __restrict__ hs, f16* __restrict__ out)
{
    int i = (blockIdx.x * 256 + threadIdx.x) * 8;
    float4 a = *(const float4*)(hs + i);
    float4 b = *(const float4*)(hs + i + 4);
    union { f16 h[8]; uint4 u; } pk;
    pk.h[0] = (f16)a.x; pk.h[1] = (f16)a.y; pk.h[2] = (f16)a.z; pk.h[3] = (f16)a.w;
    pk.h[4] = (f16)b.x; pk.h[5] = (f16)b.y; pk.h[6] = (f16)b.z; pk.h[7] = (f16)b.w;
    *(uint4*)(out + i) = pk.u;
}

// ---------------------------------------------------------------------------
// Cast ce fp32 [B,S,H] -> f16 head-split [bh][s][d]
// ---------------------------------------------------------------------------
__global__ __launch_bounds__(256) void cast_ce_kernel(
    const float* __restrict__ ce, f16* __restrict__ out)
{
    int i = (blockIdx.x * 256 + threadIdx.x) * 8;
    float4 a = *(const float4*)(ce + i);
    float4 b = *(const float4*)(ce + i + 4);
    union { f16 h[8]; uint4 u; } pk;
    pk.h[0] = (f16)a.x; pk.h[1] = (f16)a.y; pk.h[2] = (f16)a.z; pk.h[3] = (f16)a.w;
    pk.h[4] = (f16)b.x; pk.h[5] = (f16)b.y; pk.h[6] = (f16)b.z; pk.h[7] = (f16)b.w;
    int row = i >> 10, col = i & 1023;
    int bb = row >> 10, s = row & 1023;
    int h = col >> 6, d = col & 63;
    size_t o = ((((size_t)(bb * kNH + h) << 10) | s) << 6) | d;
    *(uint4*)(out + o) = pk.u;
}

// ---------------------------------------------------------------------------
// Transpose+cast W [K][N] fp32 -> Wt [N][K] f16
// ---------------------------------------------------------------------------
__global__ __launch_bounds__(256) void transpose_w_kernel(
    const float* __restrict__ Wq, const float* __restrict__ Wk,
    const float* __restrict__ Wv, f16* __restrict__ Wt)
{
    const float* W = (blockIdx.z == 0) ? Wq : (blockIdx.z == 1) ? Wk : Wv;
    f16* out = Wt + (size_t)blockIdx.z * kH * kH;
    __shared__ f16 T[64][72];
    const int tid = threadIdx.x;
    const int k0 = blockIdx.y * 64, n0 = blockIdx.x * 64;
#pragma unroll
    for (int i = 0; i < 4; ++i) {
        int idx = tid + i * 256;
        int r = idx >> 4, cb = (idx & 15) * 4;
        float4 v = *(const float4*)(W + (size_t)(k0 + r) * kH + n0 + cb);
        T[cb + 0][r] = (f16)v.x; T[cb + 1][r] = (f16)v.y;
        T[cb + 2][r] = (f16)v.z; T[cb + 3][r] = (f16)v.w;
    }
    __syncthreads();
#pragma unroll
    for (int i = 0; i < 4; ++i) {
        int idx = tid + i * 256;
        int r = idx >> 4, cb = (idx & 15) * 4;
        union { f16 h[4]; uint2 u; } pk;
#pragma unroll
        for (int j = 0; j < 4; ++j) pk.h[j] = T[r][cb + j];
        *(uint2*)(out + (size_t)(n0 + r) * kH + k0 + cb) = pk.u;
    }
}

// ---------------------------------------------------------------------------
// Transpose+cast Wcq/Wck fp32 -> f16 [n][k]
// ---------------------------------------------------------------------------
__global__ __launch_bounds__(256) void transpose_wc_kernel(
    const float* __restrict__ Wcq, const float* __restrict__ Wck,
    f16* __restrict__ Wct)
{
    const float* W = blockIdx.x ? Wck : Wcq;
    f16* out = Wct + blockIdx.x * kHD * kHD;
    const int t = threadIdx.x;
#pragma unroll
    for (int i = 0; i < 16; ++i) {
        int idx = i * 256 + t;
        int k = idx >> 6, n = idx & 63;
        out[n * 64 + k] = (f16)W[idx];
    }
}

// ---------------------------------------------------------------------------
// Per-batch mask max: mm[b] = max_s mask[b][s]
// ---------------------------------------------------------------------------
__global__ __launch_bounds__(256) void maskmax_kernel(
    const float* __restrict__ mask, float* __restrict__ mm)
{
    const int b = blockIdx.x, t = threadIdx.x;
    const float* mp = mask + b * kS;
    float v = fmaxf(fmaxf(mp[t], mp[t + 256]), fmaxf(mp[t + 512], mp[t + 768]));
#pragma unroll
    for (int off = 1; off < 64; off <<= 1) v = fmaxf(v, __shfl_xor(v, off, 64));
    __shared__ float red[4];
    if ((t & 63) == 0) red[t >> 6] = v;
    __syncthreads();
    if (t == 0) mm[b] = fmaxf(fmaxf(red[0], red[1]), fmaxf(red[2], red[3]));
}

// ---------------------------------------------------------------------------
// QKV GEMM, f16 MFMA (m97 structure) — unchanged from round 3.
// ---------------------------------------------------------------------------
__global__ __launch_bounds__(256) void qkv_gemm_f16(
    const f16* __restrict__ hs16, const f16* __restrict__ Wt,
    const float* __restrict__ bq, const float* __restrict__ bk,
    const float* __restrict__ bv,
    f16* __restrict__ q16, f16* __restrict__ k16, f16* __restrict__ vt)
{
    const int z = blockIdx.z;
    const f16* Bmat = Wt + (size_t)z * kH * kH;
    const float* bias = (z == 0) ? bq : (z == 1) ? bk : bv;

    __shared__ f16 Atile[128 * 32];
    __shared__ f16 Btile[128 * 32];

    const int tid = threadIdx.x;
    const int w = tid >> 6, lane = tid & 63;
    const int quad = lane >> 4, mh = lane & 15;
    const int wm = w >> 1, wn = w & 1;
    const int m0 = blockIdx.y * 128, n0 = blockIdx.x * 128;

    const f16* aptr[2]; const f16* bptr[2];
#pragma unroll
    for (int i = 0; i < 2; ++i) {
        int P = (w * 2 + i) * 64 + lane;
        int r2 = P >> 3, s = P & 7;
        int bb = s ^ (r2 & 7);
        int m = (r2 << 1) | (bb >> 2), c = bb & 3;
        aptr[i] = hs16 + (size_t)(m0 + m) * kH + c * 8;
        bptr[i] = Bmat + (size_t)(n0 + m) * kH + c * 8;
    }

    f32x4 acc[4][4];
#pragma unroll
    for (int i = 0; i < 4; ++i)
#pragma unroll
        for (int j = 0; j < 4; ++j) acc[i][j] = (f32x4){0.f, 0.f, 0.f, 0.f};

    int aoff[4], boff[4];
#pragma unroll
    for (int t = 0; t < 4; ++t) {
        aoff[t] = phys4(wm * 64 + t * 16 + mh, quad) * 8;
        boff[t] = phys4(wn * 64 + t * 16 + mh, quad) * 8;
    }

    for (int kt = 0; kt < 32; ++kt) {
        __syncthreads();
        async16(aptr[0], Atile + (w * 2 + 0) * 512);
        async16(aptr[1], Atile + (w * 2 + 1) * 512);
        async16(bptr[0], Btile + (w * 2 + 0) * 512);
        async16(bptr[1], Btile + (w * 2 + 1) * 512);
        aptr[0] += 32; aptr[1] += 32; bptr[0] += 32; bptr[1] += 32;
        __syncthreads();

        f16x8 af[4], bf[4];
#pragma unroll
        for (int t = 0; t < 4; ++t) af[t] = *(const f16x8*)(Atile + aoff[t]);
#pragma unroll
        for (int t = 0; t < 4; ++t) bf[t] = *(const f16x8*)(Btile + boff[t]);
#pragma unroll
        for (int i = 0; i < 4; ++i)
#pragma unroll
            for (int j = 0; j < 4; ++j)
                acc[i][j] = __builtin_amdgcn_mfma_f32_16x16x32_f16(
                    af[i], bf[j], acc[i][j], 0, 0, 0);
    }

    if (z < 2) {
        f16* outp = (z == 0) ? q16 : k16;
#pragma unroll
        for (int nt = 0; nt < 4; ++nt) {
            const int n = n0 + wn * 64 + nt * 16 + mh;
            const int h = n >> 6, d = n & 63;
            const float bn = bias[n];
#pragma unroll
            for (int mt = 0; mt < 4; ++mt) {
#pragma unroll
                for (int r = 0; r < 4; ++r) {
                    int m = m0 + wm * 64 + mt * 16 + quad * 4 + r;
                    int bbb = m >> 10, s = m & 1023;
                    outp[(((size_t)(bbb * kNH + h) * kS + s) << 6) + d] =
                        (f16)(acc[mt][nt][r] + bn);
                }
            }
        }
    } else {
#pragma unroll
        for (int nt = 0; nt < 4; ++nt) {
            const int n = n0 + wn * 64 + nt * 16 + mh;
            const int h = n >> 6, d = n & 63;
            const float bn = bias[n];
#pragma unroll
            for (int mt = 0; mt < 4; ++mt) {
                int mbase = m0 + wm * 64 + mt * 16 + quad * 4;
                int bbb = mbase >> 10, s0 = mbase & 1023;
                union { f16 h4[4]; uint2 u; } pk;
#pragma unroll
                for (int r = 0; r < 4; ++r) pk.h4[r] = (f16)(acc[mt][nt][r] + bn);
                *(uint2*)(vt + ((size_t)(bbb * kNH + h) * kHD + d) * kS + s0) = pk.u;
            }
        }
    }
}

// ---------------------------------------------------------------------------
// Context gating, MFMA. Additionally (k-side) computes max row-norm^2 of
// k_ctx per bh tile -> atomicMax into kn[bh] (for the attn softmax bound).
// ---------------------------------------------------------------------------
__global__ __launch_bounds__(256) void gate_mfma(
    const f16* __restrict__ ce16, const f16* __restrict__ Wct,
    const float* __restrict__ bcq, const float* __restrict__ bck,
    const float* __restrict__ wlqc, const float* __restrict__ wlqq,
    const float* __restrict__ wlkc, const float* __restrict__ wlkk,
    f16* __restrict__ q16, f16* __restrict__ k16,
    unsigned int* __restrict__ kn)
{
    __shared__ f16 Wls[64 * 64];
    __shared__ f16 CeQ[4][64 * 64];
    __shared__ float Tp[4][64 * 17];
    __shared__ float lamS[4][64];

    const int tid = threadIdx.x, w = tid >> 6, lane = tid & 63;
    const int quad = lane >> 4, mh = lane & 15;
    const int gate = blockIdx.x >> 9;
    const int tIdx = (blockIdx.x & 511) * 4 + w;
    const size_t row0 = (size_t)tIdx * 64;

    const float* bc  = gate ? bck  : bcq;
    const float* wlc = gate ? wlkc : wlqc;
    const float* wlx = gate ? wlkk : wlqq;
    f16* xw = (gate ? k16 : q16) + row0 * kHD;
    const f16* cep = ce16 + row0 * kHD;
    const f16* Wcg = Wct + gate * kHD * kHD;

#pragma unroll
    for (int i = 0; i < 2; ++i) {
        int P = tid + i * 256;
        int m = P >> 3, c = P & 7;
        *(uint4*)(Wls + phys8(m, c) * 8) = *(const uint4*)(Wcg + m * 64 + c * 8);
    }
#pragma unroll
    for (int i = 0; i < 8; ++i) {
        int P = i * 64 + lane;
        int m = P >> 3, c = (P & 7) ^ (m & 7);
        async16(cep + m * 64 + c * 8, CeQ[w] + i * 512);
    }
    __syncthreads();

    // xdot pass
#pragma unroll
    for (int it = 0; it < 8; ++it) {
        int slot = it * 64 + lane;
        int r = slot >> 3, c = slot & 7;
        union { uint4 u; f16 h[8]; } xv;
        xv.u = *(const uint4*)(xw + r * 64 + c * 8);
        float4 wa = ((const float4*)wlx)[c * 2];
        float4 wb = ((const float4*)wlx)[c * 2 + 1];
        float s = (float)xv.h[0] * wa.x + (float)xv.h[1] * wa.y +
                  (float)xv.h[2] * wa.z + (float)xv.h[3] * wa.w +
                  (float)xv.h[4] * wb.x + (float)xv.h[5] * wb.y +
                  (float)xv.h[6] * wb.z + (float)xv.h[7] * wb.w;
        s += __shfl_xor(s, 1, 64);
        s += __shfl_xor(s, 2, 64);
        s += __shfl_xor(s, 4, 64);
        if ((lane & 7) == 0) Tp[w][r * 17 + 16] = s;
    }

    // MFMA: ceq = ce @ Wc
    f32x4 acc[4][4];
#pragma unroll
    for (int i = 0; i < 4; ++i)
#pragma unroll
        for (int j = 0; j < 4; ++j) acc[i][j] = (f32x4){0.f, 0.f, 0.f, 0.f};

    f16x8 bfr[4][2];
#pragma unroll
    for (int nt = 0; nt < 4; ++nt)
#pragma unroll
        for (int ks = 0; ks < 2; ++ks)
            bfr[nt][ks] = *(const f16x8*)(Wls + phys8(nt * 16 + mh, ks * 4 + quad) * 8);
#pragma unroll
    for (int mt = 0; mt < 4; ++mt) {
        f16x8 a0 = *(const f16x8*)(CeQ[w] + phys8(mt * 16 + mh, 0 + quad) * 8);
        f16x8 a1 = *(const f16x8*)(CeQ[w] + phys8(mt * 16 + mh, 4 + quad) * 8);
#pragma unroll
        for (int nt = 0; nt < 4; ++nt) {
            acc[mt][nt] = __builtin_amdgcn_mfma_f32_16x16x32_f16(a0, bfr[nt][0], acc[mt][nt], 0, 0, 0);
            acc[mt][nt] = __builtin_amdgcn_mfma_f32_16x16x32_f16(a1, bfr[nt][1], acc[mt][nt], 0, 0, 0);
        }
    }

    float bcv[4], wlcv[4];
#pragma unroll
    for (int nt = 0; nt < 4; ++nt) {
        int n = nt * 16 + mh;
        bcv[nt] = bc[n]; wlcv[nt] = wlc[n];
    }
#pragma unroll
    for (int mt = 0; mt < 4; ++mt) {
#pragma unroll
        for (int r = 0; r < 4; ++r) {
            int m = mt * 16 + quad * 4 + r;
            float tpv = 0.f;
#pragma unroll
            for (int nt = 0; nt < 4; ++nt) {
                float v = acc[mt][nt][r] + bcv[nt];
                int col = nt * 16 + mh;
                CeQ[w][phys8(m, col >> 3) * 8 + (col & 7)] = (f16)v;
                tpv += v * wlcv[nt];
            }
            Tp[w][m * 17 + mh] = tpv;
        }
    }

    float t = 0.f;
#pragma unroll
    for (int j = 0; j < 17; ++j) t += Tp[w][lane * 17 + j];
    lamS[w][lane] = 1.0f / (1.0f + __expf(-t));

    // blend pass + (k-side) row-norm^2 max tracking
    float wmax = 0.f;
#pragma unroll
    for (int it = 0; it < 8; ++it) {
        int slot = it * 64 + lane;
        int r = slot >> 3, c = slot & 7;
        float lam = lamS[w][r];
        union { uint4 u; f16 h[8]; } xv;
        xv.u = *(const uint4*)(xw + r * 64 + c * 8);
        f16x8 cq = *(const f16x8*)(CeQ[w] + phys8(r, c) * 8);
        union { f16 h[8]; uint4 u; } o;
        float ss = 0.f;
#pragma unroll
        for (int j = 0; j < 8; ++j) {
            o.h[j] = (f16)((1.0f - lam) * (float)xv.h[j] + lam * (float)cq[j]);
            float fv = (float)o.h[j];
            ss += fv * fv;
        }
        *(uint4*)(xw + r * 64 + c * 8) = o.u;
        if (gate) {
            ss += __shfl_xor(ss, 1, 64);
            ss += __shfl_xor(ss, 2, 64);
            ss += __shfl_xor(ss, 4, 64);
            wmax = fmaxf(wmax, ss);
        }
    }
    if (gate) {
        wmax = fmaxf(wmax, __shfl_xor(wmax, 8, 64));
        wmax = fmaxf(wmax, __shfl_xor(wmax, 16, 64));
        wmax = fmaxf(wmax, __shfl_xor(wmax, 32, 64));
        if (lane == 0) atomicMax(&kn[tIdx >> 4], __float_as_uint(wmax));
    }
}

// ---------------------------------------------------------------------------
// MFMA flash attention with precomputed softmax bound (no online max/sum):
// bound_row = 0.125*|q_row|*|k|max + mask_max; P = exp(s + mask - bound + 10).
// Exact softmax (constant per-row shift); l reduced once at the end.
// ---------------------------------------------------------------------------
__global__ __launch_bounds__(256) void attn_f16(
    const f16* __restrict__ q16, const f16* __restrict__ k16,
    const f16* __restrict__ vt, const float* __restrict__ mask,
    const unsigned int* __restrict__ kn, const float* __restrict__ mm,
    float* __restrict__ out)
{
    __shared__ f16 Qs[64 * 64];
    __shared__ f16 Ks[64 * 64];
    __shared__ f16 Vs[64 * 64];
    __shared__ f16 Ps[4][16 * 72];

    const int tid = threadIdx.x;
    const int w = tid >> 6, lane = tid & 63;
    const int quad = lane >> 4, mh = lane & 15;
    const int bh = blockIdx.y, bbb = bh >> 4, h = bh & 15;
    const int q0 = blockIdx.x * 64;
    const float* maskb = mask + bbb * kS;

    int mS[2], cS[2];
#pragma unroll
    for (int i = 0; i < 2; ++i) {
        int P = (w * 2 + i) * 64 + lane;
        mS[i] = P >> 3;
        cS[i] = (P & 7) ^ (mS[i] & 7);
    }

#pragma unroll
    for (int i = 0; i < 2; ++i)
        async16(q16 + ((size_t)bh * kS + q0 + mS[i]) * kHD + cS[i] * 8,
                Qs + (w * 2 + i) * 512);
    __syncthreads();

    f16x8 qf[2];
#pragma unroll
    for (int ks = 0; ks < 2; ++ks)
        qf[ks] = *(const f16x8*)(Qs + phys8(w * 16 + mh, ks * 4 + quad) * 8);

    // per-row softmax bound from |q|, |k|max, mask_max (recentred by +10)
    float qn2 = 0.f;
#pragma unroll
    for (int ks = 0; ks < 2; ++ks)
#pragma unroll
        for (int j = 0; j < 8; ++j) {
            float v = (float)qf[ks][j];
            qn2 += v * v;
        }
    qn2 += __shfl_xor(qn2, 16, 64);
    qn2 += __shfl_xor(qn2, 32, 64);
    const float kn2 = __uint_as_float(kn[bh]);
    const float bnd = 0.125f * sqrtf(qn2 * kn2) + mm[bbb] - 9.5f;
    float bndr[4];
#pragma unroll
    for (int r = 0; r < 4; ++r) bndr[r] = __shfl(bnd, quad * 4 + r, 64);

    const f16* kp[2]; const f16* vp[2];
#pragma unroll
    for (int i = 0; i < 2; ++i) {
        kp[i] = k16 + ((size_t)bh * kS + mS[i]) * kHD + cS[i] * 8;
        vp[i] = vt  + ((size_t)bh * kHD + mS[i]) * kS + cS[i] * 8;
    }

    f32x4 O[4];
#pragma unroll
    for (int i = 0; i < 4; ++i) O[i] = (f32x4){0.f, 0.f, 0.f, 0.f};
    float lsum[4] = {0.f, 0.f, 0.f, 0.f};

    for (int jt = 0; jt < kS; jt += 64) {
        __syncthreads();
#pragma unroll
        for (int i = 0; i < 2; ++i) {
            async16(kp[i], Ks + (w * 2 + i) * 512);
            async16(vp[i], Vs + (w * 2 + i) * 512);
            kp[i] += 64 * kHD;
            vp[i] += 64;
        }
        __syncthreads();

        f32x4 S[4];
#pragma unroll
        for (int nt = 0; nt < 4; ++nt) {
            f16x8 kf0 = *(const f16x8*)(Ks + phys8(nt * 16 + mh, 0 + quad) * 8);
            f16x8 kf1 = *(const f16x8*)(Ks + phys8(nt * 16 + mh, 4 + quad) * 8);
            S[nt] = __builtin_amdgcn_mfma_f32_16x16x32_f16(
                qf[0], kf0, (f32x4){0.f, 0.f, 0.f, 0.f}, 0, 0, 0);
            S[nt] = __builtin_amdgcn_mfma_f32_16x16x32_f16(qf[1], kf1, S[nt], 0, 0, 0);
        }

        // P = exp(s*0.125 + mask - bound); accumulate per-lane l partials
#pragma unroll
        for (int nt = 0; nt < 4; ++nt) {
            const float mv = maskb[jt + nt * 16 + mh];
#pragma unroll
            for (int r = 0; r < 4; ++r) {
                float e = __expf(fmaf(S[nt][r], 0.125f, mv) - bndr[r]);
                lsum[r] += e;
                Ps[w][(quad * 4 + r) * 72 + nt * 16 + mh] = (f16)e;
            }
        }

        f16x8 pf[2];
#pragma unroll
        for (int ks = 0; ks < 2; ++ks)
            pf[ks] = *(const f16x8*)(&Ps[w][mh * 72 + ks * 32 + quad * 8]);

#pragma unroll
        for (int dt = 0; dt < 4; ++dt) {
            f16x8 vf0 = *(const f16x8*)(Vs + phys8(dt * 16 + mh, 0 + quad) * 8);
            f16x8 vf1 = *(const f16x8*)(Vs + phys8(dt * 16 + mh, 4 + quad) * 8);
            O[dt] = __builtin_amdgcn_mfma_f32_16x16x32_f16(pf[0], vf0, O[dt], 0, 0, 0);
            O[dt] = __builtin_amdgcn_mfma_f32_16x16x32_f16(pf[1], vf1, O[dt], 0, 0, 0);
        }
    }

    // final l reduction (once) + write
#pragma unroll
    for (int r = 0; r < 4; ++r) {
#pragma unroll
        for (int off = 1; off < 16; off <<= 1)
            lsum[r] += __shfl_xor(lsum[r], off, 64);
        lsum[r] = 1.0f / lsum[r];
    }
#pragma unroll
    for (int dt = 0; dt < 4; ++dt) {
#pragma unroll
        for (int r = 0; r < 4; ++r) {
            const int s = q0 + w * 16 + quad * 4 + r;
            out[((size_t)(bbb * kS + s)) * kH + (h << 6) + dt * 16 + mh] =
                O[dt][r] * lsum[r];
        }
    }
}

// ---------------------------------------------------------------------------
extern "C" void kernel_launch(void* const* d_in, const int* in_sizes, int n_in,
                              void* d_out, int out_size, void* d_ws, size_t ws_size,
                              hipStream_t stream) {
    (void)in_sizes; (void)n_in; (void)out_size; (void)ws_size;

    const float* hs   = (const float*)d_in[0];
    const float* mask = (const float*)d_in[1];
    const float* ce   = (const float*)d_in[2];
    const float* Wq   = (const float*)d_in[3];
    const float* bq   = (const float*)d_in[4];
    const float* Wk   = (const float*)d_in[5];
    const float* bk   = (const float*)d_in[6];
    const float* Wv   = (const float*)d_in[7];
    const float* bv   = (const float*)d_in[8];
    const float* Wcq  = (const float*)d_in[9];
    const float* bcq  = (const float*)d_in[10];
    const float* Wck  = (const float*)d_in[11];
    const float* bck  = (const float*)d_in[12];
    const float* wlqc = (const float*)d_in[13];
    const float* wlqq = (const float*)d_in[14];
    const float* wlkc = (const float*)d_in[15];
    const float* wlkk = (const float*)d_in[16];
    float* out = (float*)d_out;

    f16* hs16 = (f16*)d_ws;                            // 16.78 MB
    f16* Wt   = hs16 + (size_t)kB * kS * kH;           // 6.29 MB
    f16* q16  = Wt + (size_t)3 * kH * kH;              // 16.78 MB
    f16* k16  = q16 + (size_t)kRows * kHD;             // 16.78 MB
    f16* vt   = k16 + (size_t)kRows * kHD;             // 16.78 MB  [bh][d][s]
    f16* ce16 = vt + (size_t)kRows * kHD;              // 16.78 MB  [bh][s][d]
    f16* Wct  = ce16 + (size_t)kRows * kHD;            // 16 KB
    unsigned int* kn = (unsigned int*)(Wct + 2 * kHD * kHD);  // 128 u32
    float* mm = (float*)(kn + kBH);                    // 8 f32

    hipMemsetAsync(kn, 0, kBH * sizeof(unsigned int), stream);

    cast_hs_kernel<<<dim3(kB * kS * kH / (256 * 8)), 256, 0, stream>>>(hs, hs16);
    cast_ce_kernel<<<dim3(kB * kS * kH / (256 * 8)), 256, 0, stream>>>(ce, ce16);
    transpose_w_kernel<<<dim3(16, 16, 3), 256, 0, stream>>>(Wq, Wk, Wv, Wt);
    transpose_wc_kernel<<<dim3(2), 256, 0, stream>>>(Wcq, Wck, Wct);
    maskmax_kernel<<<dim3(kB), 256, 0, stream>>>(mask, mm);

    qkv_gemm_f16<<<dim3(kH / 128, kB * kS / 128, 3), 256, 0, stream>>>(
        hs16, Wt, bq, bk, bv, q16, k16, vt);

    gate_mfma<<<dim3(1024), 256, 0, stream>>>(
        ce16, Wct, bcq, bck, wlqc, wlqq, wlkc, wlkk, q16, k16, kn);

    attn_f16<<<dim3(kS / 64, kBH), 256, 0, stream>>>(
        q16, k16, vt, mask, kn, mm, out);
}

// Round 5
// 341.877 us; speedup vs baseline: 4.3691x; 1.0006x over previous
//
#include <hip/hip_runtime.h>

typedef _Float16 f16;
typedef f16   f16x8 __attribute__((ext_vector_type(8)));
typedef float f32x4 __attribute__((ext_vector_type(4)));

namespace {
constexpr int kB  = 8;
constexpr int kS  = 1024;
constexpr int kH  = 1024;
constexpr int kNH = 16;
constexpr int kHD = 64;
constexpr int kBH = kB * kNH;            // 128
constexpr int kRows = kBH * kS;          // 131072
}

// async global->LDS, 16B per lane; LDS dest = wave-uniform base + lane*16
__device__ __forceinline__ void async16(const f16* g, f16* l) {
    __builtin_amdgcn_global_load_lds(
        (const __attribute__((address_space(1))) unsigned int*)g,
        (__attribute__((address_space(3))) unsigned int*)l, 16, 0, 0);
}

// --- LDS chunk swizzles (16B chunks). Uniform bank-slot histogram per quad
// for MFMA fragment reads; invertible for global_load_lds staging. ---
__device__ __forceinline__ int phys4(int m, int c) {
    return ((m >> 1) << 3) | ((((m & 1) << 2) | c) ^ ((m >> 1) & 7));
}
__device__ __forceinline__ int phys8(int m, int c) {
    return (m << 3) | (c ^ (m & 7));
}

// ---------------------------------------------------------------------------
// Cast hs fp32 -> f16 (flat)
// ---------------------------------------------------------------------------
__global__ __launch_bounds__(256) void cast_hs_kernel(
    const float* __restrict__ hs, f16* __restrict__ out)
{
    int i = (blockIdx.x * 256 + threadIdx.x) * 8;
    float4 a = *(const float4*)(hs + i);
    float4 b = *(const float4*)(hs + i + 4);
    union { f16 h[8]; uint4 u; } pk;
    pk.h[0] = (f16)a.x; pk.h[1] = (f16)a.y; pk.h[2] = (f16)a.z; pk.h[3] = (f16)a.w;
    pk.h[4] = (f16)b.x; pk.h[5] = (f16)b.y; pk.h[6] = (f16)b.z; pk.h[7] = (f16)b.w;
    *(uint4*)(out + i) = pk.u;
}

// ---------------------------------------------------------------------------
// Cast ce fp32 [B,S,H] -> f16 head-split [bh][s][d]
// ---------------------------------------------------------------------------
__global__ __launch_bounds__(256) void cast_ce_kernel(
    const float* __restrict__ ce, f16* __restrict__ out)
{
    int i = (blockIdx.x * 256 + threadIdx.x) * 8;
    float4 a = *(const float4*)(ce + i);
    float4 b = *(const float4*)(ce + i + 4);
    union { f16 h[8]; uint4 u; } pk;
    pk.h[0] = (f16)a.x; pk.h[1] = (f16)a.y; pk.h[2] = (f16)a.z; pk.h[3] = (f16)a.w;
    pk.h[4] = (f16)b.x; pk.h[5] = (f16)b.y; pk.h[6] = (f16)b.z; pk.h[7] = (f16)b.w;
    int row = i >> 10, col = i & 1023;
    int bb = row >> 10, s = row & 1023;
    int h = col >> 6, d = col & 63;
    size_t o = ((((size_t)(bb * kNH + h) << 10) | s) << 6) | d;
    *(uint4*)(out + o) = pk.u;
}

// ---------------------------------------------------------------------------
// Transpose+cast W [K][N] fp32 -> Wt [N][K] f16
// ---------------------------------------------------------------------------
__global__ __launch_bounds__(256) void transpose_w_kernel(
    const float* __restrict__ Wq, const float* __restrict__ Wk,
    const float* __restrict__ Wv, f16* __restrict__ Wt)
{
    const float* W = (blockIdx.z == 0) ? Wq : (blockIdx.z == 1) ? Wk : Wv;
    f16* out = Wt + (size_t)blockIdx.z * kH * kH;
    __shared__ f16 T[64][72];
    const int tid = threadIdx.x;
    const int k0 = blockIdx.y * 64, n0 = blockIdx.x * 64;
#pragma unroll
    for (int i = 0; i < 4; ++i) {
        int idx = tid + i * 256;
        int r = idx >> 4, cb = (idx & 15) * 4;
        float4 v = *(const float4*)(W + (size_t)(k0 + r) * kH + n0 + cb);
        T[cb + 0][r] = (f16)v.x; T[cb + 1][r] = (f16)v.y;
        T[cb + 2][r] = (f16)v.z; T[cb + 3][r] = (f16)v.w;
    }
    __syncthreads();
#pragma unroll
    for (int i = 0; i < 4; ++i) {
        int idx = tid + i * 256;
        int r = idx >> 4, cb = (idx & 15) * 4;
        union { f16 h[4]; uint2 u; } pk;
#pragma unroll
        for (int j = 0; j < 4; ++j) pk.h[j] = T[r][cb + j];
        *(uint2*)(out + (size_t)(n0 + r) * kH + k0 + cb) = pk.u;
    }
}

// ---------------------------------------------------------------------------
// Transpose+cast Wcq/Wck fp32 -> f16 [n][k]
// ---------------------------------------------------------------------------
__global__ __launch_bounds__(256) void transpose_wc_kernel(
    const float* __restrict__ Wcq, const float* __restrict__ Wck,
    f16* __restrict__ Wct)
{
    const float* W = blockIdx.x ? Wck : Wcq;
    f16* out = Wct + blockIdx.x * kHD * kHD;
    const int t = threadIdx.x;
#pragma unroll
    for (int i = 0; i < 16; ++i) {
        int idx = i * 256 + t;
        int k = idx >> 6, n = idx & 63;
        out[n * 64 + k] = (f16)W[idx];
    }
}

// ---------------------------------------------------------------------------
// Per-batch mask max: mm[b] = max_s mask[b][s]
// ---------------------------------------------------------------------------
__global__ __launch_bounds__(256) void maskmax_kernel(
    const float* __restrict__ mask, float* __restrict__ mm)
{
    const int b = blockIdx.x, t = threadIdx.x;
    const float* mp = mask + b * kS;
    float v = fmaxf(fmaxf(mp[t], mp[t + 256]), fmaxf(mp[t + 512], mp[t + 768]));
#pragma unroll
    for (int off = 1; off < 64; off <<= 1) v = fmaxf(v, __shfl_xor(v, off, 64));
    __shared__ float red[4];
    if ((t & 63) == 0) red[t >> 6] = v;
    __syncthreads();
    if (t == 0) mm[b] = fmaxf(fmaxf(red[0], red[1]), fmaxf(red[2], red[3]));
}

// ---------------------------------------------------------------------------
// QKV GEMM, f16 MFMA (m97 structure). q/k epilogue goes through a per-wave
// LDS bounce (Cb, stride 20 f16: write banks {0,8,16,24}+pairs, b64-aligned)
// so global stores are 16x dwordx2 instead of 64x scalar short.
// ---------------------------------------------------------------------------
__global__ __launch_bounds__(256) void qkv_gemm_f16(
    const f16* __restrict__ hs16, const f16* __restrict__ Wt,
    const float* __restrict__ bq, const float* __restrict__ bk,
    const float* __restrict__ bv,
    f16* __restrict__ q16, f16* __restrict__ k16, f16* __restrict__ vt)
{
    const int z = blockIdx.z;
    const f16* Bmat = Wt + (size_t)z * kH * kH;
    const float* bias = (z == 0) ? bq : (z == 1) ? bk : bv;

    __shared__ f16 Atile[128 * 32];
    __shared__ f16 Btile[128 * 32];
    __shared__ f16 Cb[4][64 * 20];   // epilogue bounce

    const int tid = threadIdx.x;
    const int w = tid >> 6, lane = tid & 63;
    const int quad = lane >> 4, mh = lane & 15;
    const int wm = w >> 1, wn = w & 1;
    const int m0 = blockIdx.y * 128, n0 = blockIdx.x * 128;

    const f16* aptr[2]; const f16* bptr[2];
#pragma unroll
    for (int i = 0; i < 2; ++i) {
        int P = (w * 2 + i) * 64 + lane;
        int r2 = P >> 3, s = P & 7;
        int bb = s ^ (r2 & 7);
        int m = (r2 << 1) | (bb >> 2), c = bb & 3;
        aptr[i] = hs16 + (size_t)(m0 + m) * kH + c * 8;
        bptr[i] = Bmat + (size_t)(n0 + m) * kH + c * 8;
    }

    f32x4 acc[4][4];
#pragma unroll
    for (int i = 0; i < 4; ++i)
#pragma unroll
        for (int j = 0; j < 4; ++j) acc[i][j] = (f32x4){0.f, 0.f, 0.f, 0.f};

    int aoff[4], boff[4];
#pragma unroll
    for (int t = 0; t < 4; ++t) {
        aoff[t] = phys4(wm * 64 + t * 16 + mh, quad) * 8;
        boff[t] = phys4(wn * 64 + t * 16 + mh, quad) * 8;
    }

    for (int kt = 0; kt < 32; ++kt) {
        __syncthreads();
        async16(aptr[0], Atile + (w * 2 + 0) * 512);
        async16(aptr[1], Atile + (w * 2 + 1) * 512);
        async16(bptr[0], Btile + (w * 2 + 0) * 512);
        async16(bptr[1], Btile + (w * 2 + 1) * 512);
        aptr[0] += 32; aptr[1] += 32; bptr[0] += 32; bptr[1] += 32;
        __syncthreads();

        f16x8 af[4], bf[4];
#pragma unroll
        for (int t = 0; t < 4; ++t) af[t] = *(const f16x8*)(Atile + aoff[t]);
#pragma unroll
        for (int t = 0; t < 4; ++t) bf[t] = *(const f16x8*)(Btile + boff[t]);
#pragma unroll
        for (int i = 0; i < 4; ++i)
#pragma unroll
            for (int j = 0; j < 4; ++j)
                acc[i][j] = __builtin_amdgcn_mfma_f32_16x16x32_f16(
                    af[i], bf[j], acc[i][j], 0, 0, 0);
    }

    if (z < 2) {
        f16* outp = (z == 0) ? q16 : k16;
        const int h    = (n0 + wn * 64) >> 6;
        const int bbb  = m0 >> 10;
        const int sb   = (m0 & 1023) + wm * 64;
        f16* base = outp + ((size_t)(bbb * kNH + h) * kS + sb) * kHD;
#pragma unroll
        for (int nt = 0; nt < 4; ++nt) {
            const float bn = bias[n0 + wn * 64 + nt * 16 + mh];
            // C-layout -> bounce (banks: {0,8,16,24}+same-dword pairs)
#pragma unroll
            for (int mt = 0; mt < 4; ++mt)
#pragma unroll
                for (int r = 0; r < 4; ++r)
                    Cb[w][(mt * 16 + quad * 4 + r) * 20 + mh] =
                        (f16)(acc[mt][nt][r] + bn);
            // coalesced-ish b64 readback + dwordx2 global stores
#pragma unroll
            for (int p = 0; p < 4; ++p) {
                int row = (lane >> 2) + p * 16;
                int qtr = lane & 3;
                uint2 v = *(const uint2*)(&Cb[w][row * 20 + qtr * 4]);
                *(uint2*)(base + (size_t)row * kHD + nt * 16 + qtr * 4) = v;
            }
        }
    } else {
#pragma unroll
        for (int nt = 0; nt < 4; ++nt) {
            const int n = n0 + wn * 64 + nt * 16 + mh;
            const int h = n >> 6, d = n & 63;
            const float bn = bias[n];
#pragma unroll
            for (int mt = 0; mt < 4; ++mt) {
                int mbase = m0 + wm * 64 + mt * 16 + quad * 4;
                int bbb = mbase >> 10, s0 = mbase & 1023;
                union { f16 h4[4]; uint2 u; } pk;
#pragma unroll
                for (int r = 0; r < 4; ++r) pk.h4[r] = (f16)(acc[mt][nt][r] + bn);
                *(uint2*)(vt + ((size_t)(bbb * kNH + h) * kHD + d) * kS + s0) = pk.u;
            }
        }
    }
}

// ---------------------------------------------------------------------------
// Context gating, MFMA (unchanged from round 4). Also computes max |k_ctx|^2
// per bh -> kn[bh] for the attn softmax bound.
// ---------------------------------------------------------------------------
__global__ __launch_bounds__(256) void gate_mfma(
    const f16* __restrict__ ce16, const f16* __restrict__ Wct,
    const float* __restrict__ bcq, const float* __restrict__ bck,
    const float* __restrict__ wlqc, const float* __restrict__ wlqq,
    const float* __restrict__ wlkc, const float* __restrict__ wlkk,
    f16* __restrict__ q16, f16* __restrict__ k16,
    unsigned int* __restrict__ kn)
{
    __shared__ f16 Wls[64 * 64];
    __shared__ f16 CeQ[4][64 * 64];
    __shared__ float Tp[4][64 * 17];
    __shared__ float lamS[4][64];

    const int tid = threadIdx.x, w = tid >> 6, lane = tid & 63;
    const int quad = lane >> 4, mh = lane & 15;
    const int gate = blockIdx.x >> 9;
    const int tIdx = (blockIdx.x & 511) * 4 + w;
    const size_t row0 = (size_t)tIdx * 64;

    const float* bc  = gate ? bck  : bcq;
    const float* wlc = gate ? wlkc : wlqc;
    const float* wlx = gate ? wlkk : wlqq;
    f16* xw = (gate ? k16 : q16) + row0 * kHD;
    const f16* cep = ce16 + row0 * kHD;
    const f16* Wcg = Wct + gate * kHD * kHD;

#pragma unroll
    for (int i = 0; i < 2; ++i) {
        int P = tid + i * 256;
        int m = P >> 3, c = P & 7;
        *(uint4*)(Wls + phys8(m, c) * 8) = *(const uint4*)(Wcg + m * 64 + c * 8);
    }
#pragma unroll
    for (int i = 0; i < 8; ++i) {
        int P = i * 64 + lane;
        int m = P >> 3, c = (P & 7) ^ (m & 7);
        async16(cep + m * 64 + c * 8, CeQ[w] + i * 512);
    }
    __syncthreads();

#pragma unroll
    for (int it = 0; it < 8; ++it) {
        int slot = it * 64 + lane;
        int r = slot >> 3, c = slot & 7;
        union { uint4 u; f16 h[8]; } xv;
        xv.u = *(const uint4*)(xw + r * 64 + c * 8);
        float4 wa = ((const float4*)wlx)[c * 2];
        float4 wb = ((const float4*)wlx)[c * 2 + 1];
        float s = (float)xv.h[0] * wa.x + (float)xv.h[1] * wa.y +
                  (float)xv.h[2] * wa.z + (float)xv.h[3] * wa.w +
                  (float)xv.h[4] * wb.x + (float)xv.h[5] * wb.y +
                  (float)xv.h[6] * wb.z + (float)xv.h[7] * wb.w;
        s += __shfl_xor(s, 1, 64);
        s += __shfl_xor(s, 2, 64);
        s += __shfl_xor(s, 4, 64);
        if ((lane & 7) == 0) Tp[w][r * 17 + 16] = s;
    }

    f32x4 acc[4][4];
#pragma unroll
    for (int i = 0; i < 4; ++i)
#pragma unroll
        for (int j = 0; j < 4; ++j) acc[i][j] = (f32x4){0.f, 0.f, 0.f, 0.f};

    f16x8 bfr[4][2];
#pragma unroll
    for (int nt = 0; nt < 4; ++nt)
#pragma unroll
        for (int ks = 0; ks < 2; ++ks)
            bfr[nt][ks] = *(const f16x8*)(Wls + phys8(nt * 16 + mh, ks * 4 + quad) * 8);
#pragma unroll
    for (int mt = 0; mt < 4; ++mt) {
        f16x8 a0 = *(const f16x8*)(CeQ[w] + phys8(mt * 16 + mh, 0 + quad) * 8);
        f16x8 a1 = *(const f16x8*)(CeQ[w] + phys8(mt * 16 + mh, 4 + quad) * 8);
#pragma unroll
        for (int nt = 0; nt < 4; ++nt) {
            acc[mt][nt] = __builtin_amdgcn_mfma_f32_16x16x32_f16(a0, bfr[nt][0], acc[mt][nt], 0, 0, 0);
            acc[mt][nt] = __builtin_amdgcn_mfma_f32_16x16x32_f16(a1, bfr[nt][1], acc[mt][nt], 0, 0, 0);
        }
    }

    float bcv[4], wlcv[4];
#pragma unroll
    for (int nt = 0; nt < 4; ++nt) {
        int n = nt * 16 + mh;
        bcv[nt] = bc[n]; wlcv[nt] = wlc[n];
    }
#pragma unroll
    for (int mt = 0; mt < 4; ++mt) {
#pragma unroll
        for (int r = 0; r < 4; ++r) {
            int m = mt * 16 + quad * 4 + r;
            float tpv = 0.f;
#pragma unroll
            for (int nt = 0; nt < 4; ++nt) {
                float v = acc[mt][nt][r] + bcv[nt];
                int col = nt * 16 + mh;
                CeQ[w][phys8(m, col >> 3) * 8 + (col & 7)] = (f16)v;
                tpv += v * wlcv[nt];
            }
            Tp[w][m * 17 + mh] = tpv;
        }
    }

    float t = 0.f;
#pragma unroll
    for (int j = 0; j < 17; ++j) t += Tp[w][lane * 17 + j];
    lamS[w][lane] = 1.0f / (1.0f + __expf(-t));

    float wmax = 0.f;
#pragma unroll
    for (int it = 0; it < 8; ++it) {
        int slot = it * 64 + lane;
        int r = slot >> 3, c = slot & 7;
        float lam = lamS[w][r];
        union { uint4 u; f16 h[8]; } xv;
        xv.u = *(const uint4*)(xw + r * 64 + c * 8);
        f16x8 cq = *(const f16x8*)(CeQ[w] + phys8(r, c) * 8);
        union { f16 h[8]; uint4 u; } o;
        float ss = 0.f;
#pragma unroll
        for (int j = 0; j < 8; ++j) {
            o.h[j] = (f16)((1.0f - lam) * (float)xv.h[j] + lam * (float)cq[j]);
            float fv = (float)o.h[j];
            ss += fv * fv;
        }
        *(uint4*)(xw + r * 64 + c * 8) = o.u;
        if (gate) {
            ss += __shfl_xor(ss, 1, 64);
            ss += __shfl_xor(ss, 2, 64);
            ss += __shfl_xor(ss, 4, 64);
            wmax = fmaxf(wmax, ss);
        }
    }
    if (gate) {
        wmax = fmaxf(wmax, __shfl_xor(wmax, 8, 64));
        wmax = fmaxf(wmax, __shfl_xor(wmax, 16, 64));
        wmax = fmaxf(wmax, __shfl_xor(wmax, 32, 64));
        if (lane == 0) atomicMax(&kn[tIdx >> 4], __float_as_uint(wmax));
    }
}

// ---------------------------------------------------------------------------
// MFMA flash attention, bound-softmax, R=2: 128 q-rows/block, 32/wave.
// K/V fragment reads + barriers amortized over 2 row-tiles; Ps stride 68.
// Q pre-scaled by 0.125 (per-element fmaf -> add3).
// ---------------------------------------------------------------------------
__global__ __launch_bounds__(256) void attn_f16(
    const f16* __restrict__ q16, const f16* __restrict__ k16,
    const f16* __restrict__ vt, const float* __restrict__ mask,
    const unsigned int* __restrict__ kn, const float* __restrict__ mm,
    float* __restrict__ out)
{
    __shared__ f16 Qs[128 * 64];
    __shared__ f16 Ks[64 * 64];
    __shared__ f16 Vs[64 * 64];
    __shared__ f16 Ps[4][32 * 68];   // rows stride 68 f16 = 34 dwords

    const int tid = threadIdx.x;
    const int w = tid >> 6, lane = tid & 63;
    const int quad = lane >> 4, mh = lane & 15;
    const int bh = blockIdx.y, bbb = bh >> 4, h = bh & 15;
    const int q0 = blockIdx.x * 128;
    const float* maskb = mask + bbb * kS;

    // stage Q (each wave stages its own 32 rows): 4 issues/wave
#pragma unroll
    for (int i = 0; i < 4; ++i) {
        int P = (w * 4 + i) * 64 + lane;
        int m = P >> 3, c = (P & 7) ^ (m & 7);
        async16(q16 + ((size_t)bh * kS + q0 + m) * kHD + c * 8,
                Qs + (w * 4 + i) * 512);
    }

    // K/V staging coords (2 issues/wave over 64-row tiles)
    int mS[2], cS[2];
#pragma unroll
    for (int i = 0; i < 2; ++i) {
        int P = (w * 2 + i) * 64 + lane;
        mS[i] = P >> 3;
        cS[i] = (P & 7) ^ (mS[i] & 7);
    }
    const f16* kp[2]; const f16* vp[2];
#pragma unroll
    for (int i = 0; i < 2; ++i) {
        kp[i] = k16 + ((size_t)bh * kS + mS[i]) * kHD + cS[i] * 8;
        vp[i] = vt  + ((size_t)bh * kHD + mS[i]) * kS + cS[i] * 8;
    }
    __syncthreads();

    f16x8 qf[2][2];
#pragma unroll
    for (int rt = 0; rt < 2; ++rt)
#pragma unroll
        for (int ks = 0; ks < 2; ++ks) {
            qf[rt][ks] = *(const f16x8*)(
                Qs + phys8(w * 32 + rt * 16 + mh, ks * 4 + quad) * 8);
#pragma unroll
            for (int j = 0; j < 8; ++j) qf[rt][ks][j] *= (f16)0.125f;
        }

    // per-row softmax bound: |q*0.125| * |k|max + mask_max - 9.5
    const float kn2 = __uint_as_float(kn[bh]);
    const float mmb = mm[bbb];
    float bndr[2][4];
#pragma unroll
    for (int rt = 0; rt < 2; ++rt) {
        float qn2 = 0.f;
#pragma unroll
        for (int ks = 0; ks < 2; ++ks)
#pragma unroll
            for (int j = 0; j < 8; ++j) {
                float v = (float)qf[rt][ks][j];
                qn2 += v * v;
            }
        qn2 += __shfl_xor(qn2, 16, 64);
        qn2 += __shfl_xor(qn2, 32, 64);
        const float bnd = sqrtf(qn2 * kn2) + mmb - 9.5f;
#pragma unroll
        for (int r = 0; r < 4; ++r) bndr[rt][r] = __shfl(bnd, quad * 4 + r, 64);
    }

    f32x4 O[2][4];
#pragma unroll
    for (int rt = 0; rt < 2; ++rt)
#pragma unroll
        for (int i = 0; i < 4; ++i) O[rt][i] = (f32x4){0.f, 0.f, 0.f, 0.f};
    float lsum[2][4] = {{0.f, 0.f, 0.f, 0.f}, {0.f, 0.f, 0.f, 0.f}};

    for (int jt = 0; jt < kS; jt += 64) {
        __syncthreads();
#pragma unroll
        for (int i = 0; i < 2; ++i) {
            async16(kp[i], Ks + (w * 2 + i) * 512);
            async16(vp[i], Vs + (w * 2 + i) * 512);
            kp[i] += 64 * kHD;
            vp[i] += 64;
        }
        __syncthreads();

        // S = (0.125 Q) K^T
        f32x4 S[2][4];
#pragma unroll
        for (int nt = 0; nt < 4; ++nt) {
            f16x8 kf0 = *(const f16x8*)(Ks + phys8(nt * 16 + mh, 0 + quad) * 8);
            f16x8 kf1 = *(const f16x8*)(Ks + phys8(nt * 16 + mh, 4 + quad) * 8);
#pragma unroll
            for (int rt = 0; rt < 2; ++rt) {
                S[rt][nt] = __builtin_amdgcn_mfma_f32_16x16x32_f16(
                    qf[rt][0], kf0, (f32x4){0.f, 0.f, 0.f, 0.f}, 0, 0, 0);
                S[rt][nt] = __builtin_amdgcn_mfma_f32_16x16x32_f16(
                    qf[rt][1], kf1, S[rt][nt], 0, 0, 0);
            }
        }

        // P = exp(s + mask - bound); per-lane l partials
#pragma unroll
        for (int nt = 0; nt < 4; ++nt) {
            const float mv = maskb[jt + nt * 16 + mh];
#pragma unroll
            for (int rt = 0; rt < 2; ++rt)
#pragma unroll
                for (int r = 0; r < 4; ++r) {
                    float e = __expf(S[rt][nt][r] + mv - bndr[rt][r]);
                    lsum[rt][r] += e;
                    Ps[w][(rt * 16 + quad * 4 + r) * 68 + nt * 16 + mh] = (f16)e;
                }
        }

        f16x8 pf[2][2];
#pragma unroll
        for (int rt = 0; rt < 2; ++rt)
#pragma unroll
            for (int ks = 0; ks < 2; ++ks)
                pf[rt][ks] = *(const f16x8*)(
                    &Ps[w][(rt * 16 + mh) * 68 + ks * 32 + quad * 8]);

        // O += P V
#pragma unroll
        for (int dt = 0; dt < 4; ++dt) {
            f16x8 vf0 = *(const f16x8*)(Vs + phys8(dt * 16 + mh, 0 + quad) * 8);
            f16x8 vf1 = *(const f16x8*)(Vs + phys8(dt * 16 + mh, 4 + quad) * 8);
#pragma unroll
            for (int rt = 0; rt < 2; ++rt) {
                O[rt][dt] = __builtin_amdgcn_mfma_f32_16x16x32_f16(
                    pf[rt][0], vf0, O[rt][dt], 0, 0, 0);
                O[rt][dt] = __builtin_amdgcn_mfma_f32_16x16x32_f16(
                    pf[rt][1], vf1, O[rt][dt], 0, 0, 0);
            }
        }
    }

    // final l reduction + write
#pragma unroll
    for (int rt = 0; rt < 2; ++rt)
#pragma unroll
        for (int r = 0; r < 4; ++r) {
#pragma unroll
            for (int off = 1; off < 16; off <<= 1)
                lsum[rt][r] += __shfl_xor(lsum[rt][r], off, 64);
            lsum[rt][r] = 1.0f / lsum[rt][r];
        }
#pragma unroll
    for (int rt = 0; rt < 2; ++rt)
#pragma unroll
        for (int dt = 0; dt < 4; ++dt)
#pragma unroll
            for (int r = 0; r < 4; ++r) {
                const int s = q0 + w * 32 + rt * 16 + quad * 4 + r;
                out[((size_t)(bbb * kS + s)) * kH + (h << 6) + dt * 16 + mh] =
                    O[rt][dt][r] * lsum[rt][r];
            }
}

// ---------------------------------------------------------------------------
extern "C" void kernel_launch(void* const* d_in, const int* in_sizes, int n_in,
                              void* d_out, int out_size, void* d_ws, size_t ws_size,
                              hipStream_t stream) {
    (void)in_sizes; (void)n_in; (void)out_size; (void)ws_size;

    const float* hs   = (const float*)d_in[0];
    const float* mask = (const float*)d_in[1];
    const float* ce   = (const float*)d_in[2];
    const float* Wq   = (const float*)d_in[3];
    const float* bq   = (const float*)d_in[4];
    const float* Wk   = (const float*)d_in[5];
    const float* bk   = (const float*)d_in[6];
    const float* Wv   = (const float*)d_in[7];
    const float* bv   = (const float*)d_in[8];
    const float* Wcq  = (const float*)d_in[9];
    const float* bcq  = (const float*)d_in[10];
    const float* Wck  = (const float*)d_in[11];
    const float* bck  = (const float*)d_in[12];
    const float* wlqc = (const float*)d_in[13];
    const float* wlqq = (const float*)d_in[14];
    const float* wlkc = (const float*)d_in[15];
    const float* wlkk = (const float*)d_in[16];
    float* out = (float*)d_out;

    f16* hs16 = (f16*)d_ws;                            // 16.78 MB
    f16* Wt   = hs16 + (size_t)kB * kS * kH;           // 6.29 MB
    f16* q16  = Wt + (size_t)3 * kH * kH;              // 16.78 MB
    f16* k16  = q16 + (size_t)kRows * kHD;             // 16.78 MB
    f16* vt   = k16 + (size_t)kRows * kHD;             // 16.78 MB  [bh][d][s]
    f16* ce16 = vt + (size_t)kRows * kHD;              // 16.78 MB  [bh][s][d]
    f16* Wct  = ce16 + (size_t)kRows * kHD;            // 16 KB
    unsigned int* kn = (unsigned int*)(Wct + 2 * kHD * kHD);  // 128 u32
    float* mm = (float*)(kn + kBH);                    // 8 f32

    hipMemsetAsync(kn, 0, kBH * sizeof(unsigned int), stream);

    cast_hs_kernel<<<dim3(kB * kS * kH / (256 * 8)), 256, 0, stream>>>(hs, hs16);
    cast_ce_kernel<<<dim3(kB * kS * kH / (256 * 8)), 256, 0, stream>>>(ce, ce16);
    transpose_w_kernel<<<dim3(16, 16, 3), 256, 0, stream>>>(Wq, Wk, Wv, Wt);
    transpose_wc_kernel<<<dim3(2), 256, 0, stream>>>(Wcq, Wck, Wct);
    maskmax_kernel<<<dim3(kB), 256, 0, stream>>>(mask, mm);

    qkv_gemm_f16<<<dim3(kH / 128, kB * kS / 128, 3), 256, 0, stream>>>(
        hs16, Wt, bq, bk, bv, q16, k16, vt);

    gate_mfma<<<dim3(1024), 256, 0, stream>>>(
        ce16, Wct, bcq, bck, wlqc, wlqq, wlkc, wlkk, q16, k16, kn);

    attn_f16<<<dim3(kS / 128, kBH), 256, 0, stream>>>(
        q16, k16, vt, mask, kn, mm, out);
}

// Round 6
// 319.391 us; speedup vs baseline: 4.6767x; 1.0704x over previous
//
#include <hip/hip_runtime.h>

typedef _Float16 f16;
typedef f16   f16x8 __attribute__((ext_vector_type(8)));
typedef float f32x4 __attribute__((ext_vector_type(4)));

namespace {
constexpr int kB  = 8;
constexpr int kS  = 1024;
constexpr int kH  = 1024;
constexpr int kNH = 16;
constexpr int kHD = 64;
constexpr int kBH = kB * kNH;            // 128
constexpr int kRows = kBH * kS;          // 131072
}

// async global->LDS, 16B per lane; LDS dest = wave-uniform base + lane*16
__device__ __forceinline__ void async16(const f16* g, f16* l) {
    __builtin_amdgcn_global_load_lds(
        (const __attribute__((address_space(1))) unsigned int*)g,
        (__attribute__((address_space(3))) unsigned int*)l, 16, 0, 0);
}

// --- LDS chunk swizzles (16B chunks). Uniform bank-slot histogram per quad
// for MFMA fragment reads; invertible for global_load_lds staging. ---
__device__ __forceinline__ int phys4(int m, int c) {
    return ((m >> 1) << 3) | ((((m & 1) << 2) | c) ^ ((m >> 1) & 7));
}
__device__ __forceinline__ int phys8(int m, int c) {
    return (m << 3) | (c ^ (m & 7));
}

// ---------------------------------------------------------------------------
// Merged input casts: y=0 hs fp32 -> f16 flat; y=1 ce fp32 -> f16 head-split
// ---------------------------------------------------------------------------
__global__ __launch_bounds__(256) void cast_inputs_kernel(
    const float* __restrict__ hs, const float* __restrict__ ce,
    f16* __restrict__ hs16, f16* __restrict__ ce16)
{
    int i = (blockIdx.x * 256 + threadIdx.x) * 8;
    const float* src = blockIdx.y ? ce : hs;
    float4 a = *(const float4*)(src + i);
    float4 b = *(const float4*)(src + i + 4);
    union { f16 h[8]; uint4 u; } pk;
    pk.h[0] = (f16)a.x; pk.h[1] = (f16)a.y; pk.h[2] = (f16)a.z; pk.h[3] = (f16)a.w;
    pk.h[4] = (f16)b.x; pk.h[5] = (f16)b.y; pk.h[6] = (f16)b.z; pk.h[7] = (f16)b.w;
    if (blockIdx.y == 0) {
        *(uint4*)(hs16 + i) = pk.u;
    } else {
        int row = i >> 10, col = i & 1023;
        int bb = row >> 10, s = row & 1023;
        int h = col >> 6, d = col & 63;
        size_t o = ((((size_t)(bb * kNH + h) << 10) | s) << 6) | d;
        *(uint4*)(ce16 + o) = pk.u;
    }
}

// ---------------------------------------------------------------------------
// Transpose+cast W [K][N] fp32 -> Wt [N][K] f16
// ---------------------------------------------------------------------------
__global__ __launch_bounds__(256) void transpose_w_kernel(
    const float* __restrict__ Wq, const float* __restrict__ Wk,
    const float* __restrict__ Wv, f16* __restrict__ Wt)
{
    const float* W = (blockIdx.z == 0) ? Wq : (blockIdx.z == 1) ? Wk : Wv;
    f16* out = Wt + (size_t)blockIdx.z * kH * kH;
    __shared__ f16 T[64][72];
    const int tid = threadIdx.x;
    const int k0 = blockIdx.y * 64, n0 = blockIdx.x * 64;
#pragma unroll
    for (int i = 0; i < 4; ++i) {
        int idx = tid + i * 256;
        int r = idx >> 4, cb = (idx & 15) * 4;
        float4 v = *(const float4*)(W + (size_t)(k0 + r) * kH + n0 + cb);
        T[cb + 0][r] = (f16)v.x; T[cb + 1][r] = (f16)v.y;
        T[cb + 2][r] = (f16)v.z; T[cb + 3][r] = (f16)v.w;
    }
    __syncthreads();
#pragma unroll
    for (int i = 0; i < 4; ++i) {
        int idx = tid + i * 256;
        int r = idx >> 4, cb = (idx & 15) * 4;
        union { f16 h[4]; uint2 u; } pk;
#pragma unroll
        for (int j = 0; j < 4; ++j) pk.h[j] = T[r][cb + j];
        *(uint2*)(out + (size_t)(n0 + r) * kH + k0 + cb) = pk.u;
    }
}

// ---------------------------------------------------------------------------
// Transpose+cast Wcq/Wck fp32 -> f16 [n][k]
// ---------------------------------------------------------------------------
__global__ __launch_bounds__(256) void transpose_wc_kernel(
    const float* __restrict__ Wcq, const float* __restrict__ Wck,
    f16* __restrict__ Wct)
{
    const float* W = blockIdx.x ? Wck : Wcq;
    f16* out = Wct + blockIdx.x * kHD * kHD;
    const int t = threadIdx.x;
#pragma unroll
    for (int i = 0; i < 16; ++i) {
        int idx = i * 256 + t;
        int k = idx >> 6, n = idx & 63;
        out[n * 64 + k] = (f16)W[idx];
    }
}

// ---------------------------------------------------------------------------
// Per-batch mask max: mm[b] = max_s mask[b][s]
// ---------------------------------------------------------------------------
__global__ __launch_bounds__(256) void maskmax_kernel(
    const float* __restrict__ mask, float* __restrict__ mm)
{
    const int b = blockIdx.x, t = threadIdx.x;
    const float* mp = mask + b * kS;
    float v = fmaxf(fmaxf(mp[t], mp[t + 256]), fmaxf(mp[t + 512], mp[t + 768]));
#pragma unroll
    for (int off = 1; off < 64; off <<= 1) v = fmaxf(v, __shfl_xor(v, off, 64));
    __shared__ float red[4];
    if ((t & 63) == 0) red[t >> 6] = v;
    __syncthreads();
    if (t == 0) mm[b] = fmaxf(fmaxf(red[0], red[1]), fmaxf(red[2], red[3]));
}

// ---------------------------------------------------------------------------
// QKV GEMM, f16 MFMA. Grid (m, n, z): A-reuse (dID=64) and B-reuse (dID=8)
// both XCD-local under round-robin dispatch.
// ---------------------------------------------------------------------------
__global__ __launch_bounds__(256) void qkv_gemm_f16(
    const f16* __restrict__ hs16, const f16* __restrict__ Wt,
    const float* __restrict__ bq, const float* __restrict__ bk,
    const float* __restrict__ bv,
    f16* __restrict__ q16, f16* __restrict__ k16, f16* __restrict__ vt)
{
    const int z = blockIdx.z;
    const f16* Bmat = Wt + (size_t)z * kH * kH;
    const float* bias = (z == 0) ? bq : (z == 1) ? bk : bv;

    __shared__ f16 Atile[128 * 32];
    __shared__ f16 Btile[128 * 32];
    __shared__ f16 Cb[4][64 * 20];   // epilogue bounce

    const int tid = threadIdx.x;
    const int w = tid >> 6, lane = tid & 63;
    const int quad = lane >> 4, mh = lane & 15;
    const int wm = w >> 1, wn = w & 1;
    const int m0 = blockIdx.x * 128, n0 = blockIdx.y * 128;

    const f16* aptr[2]; const f16* bptr[2];
#pragma unroll
    for (int i = 0; i < 2; ++i) {
        int P = (w * 2 + i) * 64 + lane;
        int r2 = P >> 3, s = P & 7;
        int bb = s ^ (r2 & 7);
        int m = (r2 << 1) | (bb >> 2), c = bb & 3;
        aptr[i] = hs16 + (size_t)(m0 + m) * kH + c * 8;
        bptr[i] = Bmat + (size_t)(n0 + m) * kH + c * 8;
    }

    f32x4 acc[4][4];
#pragma unroll
    for (int i = 0; i < 4; ++i)
#pragma unroll
        for (int j = 0; j < 4; ++j) acc[i][j] = (f32x4){0.f, 0.f, 0.f, 0.f};

    int aoff[4], boff[4];
#pragma unroll
    for (int t = 0; t < 4; ++t) {
        aoff[t] = phys4(wm * 64 + t * 16 + mh, quad) * 8;
        boff[t] = phys4(wn * 64 + t * 16 + mh, quad) * 8;
    }

    for (int kt = 0; kt < 32; ++kt) {
        __syncthreads();
        async16(aptr[0], Atile + (w * 2 + 0) * 512);
        async16(aptr[1], Atile + (w * 2 + 1) * 512);
        async16(bptr[0], Btile + (w * 2 + 0) * 512);
        async16(bptr[1], Btile + (w * 2 + 1) * 512);
        aptr[0] += 32; aptr[1] += 32; bptr[0] += 32; bptr[1] += 32;
        __syncthreads();

        f16x8 af[4], bf[4];
#pragma unroll
        for (int t = 0; t < 4; ++t) af[t] = *(const f16x8*)(Atile + aoff[t]);
#pragma unroll
        for (int t = 0; t < 4; ++t) bf[t] = *(const f16x8*)(Btile + boff[t]);
#pragma unroll
        for (int i = 0; i < 4; ++i)
#pragma unroll
            for (int j = 0; j < 4; ++j)
                acc[i][j] = __builtin_amdgcn_mfma_f32_16x16x32_f16(
                    af[i], bf[j], acc[i][j], 0, 0, 0);
    }

    if (z < 2) {
        f16* outp = (z == 0) ? q16 : k16;
        const int h    = (n0 + wn * 64) >> 6;
        const int bbb  = m0 >> 10;
        const int sb   = (m0 & 1023) + wm * 64;
        f16* base = outp + ((size_t)(bbb * kNH + h) * kS + sb) * kHD;
#pragma unroll
        for (int nt = 0; nt < 4; ++nt) {
            const float bn = bias[n0 + wn * 64 + nt * 16 + mh];
#pragma unroll
            for (int mt = 0; mt < 4; ++mt)
#pragma unroll
                for (int r = 0; r < 4; ++r)
                    Cb[w][(mt * 16 + quad * 4 + r) * 20 + mh] =
                        (f16)(acc[mt][nt][r] + bn);
#pragma unroll
            for (int p = 0; p < 4; ++p) {
                int row = (lane >> 2) + p * 16;
                int qtr = lane & 3;
                uint2 v = *(const uint2*)(&Cb[w][row * 20 + qtr * 4]);
                *(uint2*)(base + (size_t)row * kHD + nt * 16 + qtr * 4) = v;
            }
        }
    } else {
#pragma unroll
        for (int nt = 0; nt < 4; ++nt) {
            const int n = n0 + wn * 64 + nt * 16 + mh;
            const int h = n >> 6, d = n & 63;
            const float bn = bias[n];
#pragma unroll
            for (int mt = 0; mt < 4; ++mt) {
                int mbase = m0 + wm * 64 + mt * 16 + quad * 4;
                int bbb = mbase >> 10, s0 = mbase & 1023;
                union { f16 h4[4]; uint2 u; } pk;
#pragma unroll
                for (int r = 0; r < 4; ++r) pk.h4[r] = (f16)(acc[mt][nt][r] + bn);
                *(uint2*)(vt + ((size_t)(bbb * kNH + h) * kHD + d) * kS + s0) = pk.u;
            }
        }
    }
}

// ---------------------------------------------------------------------------
// Context gating, MFMA (unchanged). Also computes max |k_ctx|^2 per bh.
// ---------------------------------------------------------------------------
__global__ __launch_bounds__(256) void gate_mfma(
    const f16* __restrict__ ce16, const f16* __restrict__ Wct,
    const float* __restrict__ bcq, const float* __restrict__ bck,
    const float* __restrict__ wlqc, const float* __restrict__ wlqq,
    const float* __restrict__ wlkc, const float* __restrict__ wlkk,
    f16* __restrict__ q16, f16* __restrict__ k16,
    unsigned int* __restrict__ kn)
{
    __shared__ f16 Wls[64 * 64];
    __shared__ f16 CeQ[4][64 * 64];
    __shared__ float Tp[4][64 * 17];
    __shared__ float lamS[4][64];

    const int tid = threadIdx.x, w = tid >> 6, lane = tid & 63;
    const int quad = lane >> 4, mh = lane & 15;
    const int gate = blockIdx.x >> 9;
    const int tIdx = (blockIdx.x & 511) * 4 + w;
    const size_t row0 = (size_t)tIdx * 64;

    const float* bc  = gate ? bck  : bcq;
    const float* wlc = gate ? wlkc : wlqc;
    const float* wlx = gate ? wlkk : wlqq;
    f16* xw = (gate ? k16 : q16) + row0 * kHD;
    const f16* cep = ce16 + row0 * kHD;
    const f16* Wcg = Wct + gate * kHD * kHD;

#pragma unroll
    for (int i = 0; i < 2; ++i) {
        int P = tid + i * 256;
        int m = P >> 3, c = P & 7;
        *(uint4*)(Wls + phys8(m, c) * 8) = *(const uint4*)(Wcg + m * 64 + c * 8);
    }
#pragma unroll
    for (int i = 0; i < 8; ++i) {
        int P = i * 64 + lane;
        int m = P >> 3, c = (P & 7) ^ (m & 7);
        async16(cep + m * 64 + c * 8, CeQ[w] + i * 512);
    }
    __syncthreads();

#pragma unroll
    for (int it = 0; it < 8; ++it) {
        int slot = it * 64 + lane;
        int r = slot >> 3, c = slot & 7;
        union { uint4 u; f16 h[8]; } xv;
        xv.u = *(const uint4*)(xw + r * 64 + c * 8);
        float4 wa = ((const float4*)wlx)[c * 2];
        float4 wb = ((const float4*)wlx)[c * 2 + 1];
        float s = (float)xv.h[0] * wa.x + (float)xv.h[1] * wa.y +
                  (float)xv.h[2] * wa.z + (float)xv.h[3] * wa.w +
                  (float)xv.h[4] * wb.x + (float)xv.h[5] * wb.y +
                  (float)xv.h[6] * wb.z + (float)xv.h[7] * wb.w;
        s += __shfl_xor(s, 1, 64);
        s += __shfl_xor(s, 2, 64);
        s += __shfl_xor(s, 4, 64);
        if ((lane & 7) == 0) Tp[w][r * 17 + 16] = s;
    }

    f32x4 acc[4][4];
#pragma unroll
    for (int i = 0; i < 4; ++i)
#pragma unroll
        for (int j = 0; j < 4; ++j) acc[i][j] = (f32x4){0.f, 0.f, 0.f, 0.f};

    f16x8 bfr[4][2];
#pragma unroll
    for (int nt = 0; nt < 4; ++nt)
#pragma unroll
        for (int ks = 0; ks < 2; ++ks)
            bfr[nt][ks] = *(const f16x8*)(Wls + phys8(nt * 16 + mh, ks * 4 + quad) * 8);
#pragma unroll
    for (int mt = 0; mt < 4; ++mt) {
        f16x8 a0 = *(const f16x8*)(CeQ[w] + phys8(mt * 16 + mh, 0 + quad) * 8);
        f16x8 a1 = *(const f16x8*)(CeQ[w] + phys8(mt * 16 + mh, 4 + quad) * 8);
#pragma unroll
        for (int nt = 0; nt < 4; ++nt) {
            acc[mt][nt] = __builtin_amdgcn_mfma_f32_16x16x32_f16(a0, bfr[nt][0], acc[mt][nt], 0, 0, 0);
            acc[mt][nt] = __builtin_amdgcn_mfma_f32_16x16x32_f16(a1, bfr[nt][1], acc[mt][nt], 0, 0, 0);
        }
    }

    float bcv[4], wlcv[4];
#pragma unroll
    for (int nt = 0; nt < 4; ++nt) {
        int n = nt * 16 + mh;
        bcv[nt] = bc[n]; wlcv[nt] = wlc[n];
    }
#pragma unroll
    for (int mt = 0; mt < 4; ++mt) {
#pragma unroll
        for (int r = 0; r < 4; ++r) {
            int m = mt * 16 + quad * 4 + r;
            float tpv = 0.f;
#pragma unroll
            for (int nt = 0; nt < 4; ++nt) {
                float v = acc[mt][nt][r] + bcv[nt];
                int col = nt * 16 + mh;
                CeQ[w][phys8(m, col >> 3) * 8 + (col & 7)] = (f16)v;
                tpv += v * wlcv[nt];
            }
            Tp[w][m * 17 + mh] = tpv;
        }
    }

    float t = 0.f;
#pragma unroll
    for (int j = 0; j < 17; ++j) t += Tp[w][lane * 17 + j];
    lamS[w][lane] = 1.0f / (1.0f + __expf(-t));

    float wmax = 0.f;
#pragma unroll
    for (int it = 0; it < 8; ++it) {
        int slot = it * 64 + lane;
        int r = slot >> 3, c = slot & 7;
        float lam = lamS[w][r];
        union { uint4 u; f16 h[8]; } xv;
        xv.u = *(const uint4*)(xw + r * 64 + c * 8);
        f16x8 cq = *(const f16x8*)(CeQ[w] + phys8(r, c) * 8);
        union { f16 h[8]; uint4 u; } o;
        float ss = 0.f;
#pragma unroll
        for (int j = 0; j < 8; ++j) {
            o.h[j] = (f16)((1.0f - lam) * (float)xv.h[j] + lam * (float)cq[j]);
            float fv = (float)o.h[j];
            ss += fv * fv;
        }
        *(uint4*)(xw + r * 64 + c * 8) = o.u;
        if (gate) {
            ss += __shfl_xor(ss, 1, 64);
            ss += __shfl_xor(ss, 2, 64);
            ss += __shfl_xor(ss, 4, 64);
            wmax = fmaxf(wmax, ss);
        }
    }
    if (gate) {
        wmax = fmaxf(wmax, __shfl_xor(wmax, 8, 64));
        wmax = fmaxf(wmax, __shfl_xor(wmax, 16, 64));
        wmax = fmaxf(wmax, __shfl_xor(wmax, 32, 64));
        if (lane == 0) atomicMax(&kn[tIdx >> 4], __float_as_uint(wmax));
    }
}

// ---------------------------------------------------------------------------
// MFMA flash attention, bound-softmax, R=2, K/V DOUBLE-BUFFERED.
// Grid (bh, qblk): same-bh blocks land on the same XCD (dID = 128 = 0 mod 8)
// so K/V stay L2-resident. Q fragments loaded global->reg (no Q LDS).
// Prefetch of tile jt+64 is issued BEFORE computing jt; the end-of-iter
// barrier's vmcnt(0) drain then overlaps with a full tile of compute.
// ---------------------------------------------------------------------------
__global__ __launch_bounds__(256) void attn_f16(
    const f16* __restrict__ q16, const f16* __restrict__ k16,
    const f16* __restrict__ vt, const float* __restrict__ mask,
    const unsigned int* __restrict__ kn, const float* __restrict__ mm,
    float* __restrict__ out)
{
    __shared__ f16 Ks[2][64 * 64];
    __shared__ f16 Vs[2][64 * 64];
    __shared__ f16 Ps[4][32 * 68];   // rows stride 68 f16 = 34 dwords

    const int tid = threadIdx.x;
    const int w = tid >> 6, lane = tid & 63;
    const int quad = lane >> 4, mh = lane & 15;
    const int bh = blockIdx.x, bbb = bh >> 4, h = bh & 15;
    const int q0 = blockIdx.y * 128;
    const float* maskb = mask + bbb * kS;

    // K/V staging coords (2 issues/wave over 64-row tiles)
    int mS[2], cS[2];
#pragma unroll
    for (int i = 0; i < 2; ++i) {
        int P = (w * 2 + i) * 64 + lane;
        mS[i] = P >> 3;
        cS[i] = (P & 7) ^ (mS[i] & 7);
    }
    const f16* kp[2]; const f16* vp[2];
#pragma unroll
    for (int i = 0; i < 2; ++i) {
        kp[i] = k16 + ((size_t)bh * kS + mS[i]) * kHD + cS[i] * 8;
        vp[i] = vt  + ((size_t)bh * kHD + mS[i]) * kS + cS[i] * 8;
    }

    auto issue = [&](f16* Kb, f16* Vb) {
#pragma unroll
        for (int i = 0; i < 2; ++i) {
            async16(kp[i], Kb + (w * 2 + i) * 512);
            async16(vp[i], Vb + (w * 2 + i) * 512);
            kp[i] += 64 * kHD;
            vp[i] += 64;
        }
    };

    // stage tile 0 into buffer 0
    issue(Ks[0], Vs[0]);

    // Q fragments: direct global->reg, pre-scaled by 0.125
    f16x8 qf[2][2];
#pragma unroll
    for (int rt = 0; rt < 2; ++rt) {
        const f16* qrow = q16 + ((size_t)bh * kS + q0 + w * 32 + rt * 16 + mh) * kHD;
#pragma unroll
        for (int ks = 0; ks < 2; ++ks) {
            qf[rt][ks] = *(const f16x8*)(qrow + ks * 32 + quad * 8);
#pragma unroll
            for (int j = 0; j < 8; ++j) qf[rt][ks][j] *= (f16)0.125f;
        }
    }

    // per-row softmax bound: |q*0.125| * |k|max + mask_max - 9.5
    const float kn2 = __uint_as_float(kn[bh]);
    const float mmb = mm[bbb];
    float bndr[2][4];
#pragma unroll
    for (int rt = 0; rt < 2; ++rt) {
        float qn2 = 0.f;
#pragma unroll
        for (int ks = 0; ks < 2; ++ks)
#pragma unroll
            for (int j = 0; j < 8; ++j) {
                float v = (float)qf[rt][ks][j];
                qn2 += v * v;
            }
        qn2 += __shfl_xor(qn2, 16, 64);
        qn2 += __shfl_xor(qn2, 32, 64);
        const float bnd = sqrtf(qn2 * kn2) + mmb - 9.5f;
#pragma unroll
        for (int r = 0; r < 4; ++r) bndr[rt][r] = __shfl(bnd, quad * 4 + r, 64);
    }

    f32x4 O[2][4];
#pragma unroll
    for (int rt = 0; rt < 2; ++rt)
#pragma unroll
        for (int i = 0; i < 4; ++i) O[rt][i] = (f32x4){0.f, 0.f, 0.f, 0.f};
    float lsum[2][4] = {{0.f, 0.f, 0.f, 0.f}, {0.f, 0.f, 0.f, 0.f}};

    auto step = [&](const f16* Kb, const f16* Vb, int jt) {
        f32x4 S[2][4];
#pragma unroll
        for (int nt = 0; nt < 4; ++nt) {
            f16x8 kf0 = *(const f16x8*)(Kb + phys8(nt * 16 + mh, 0 + quad) * 8);
            f16x8 kf1 = *(const f16x8*)(Kb + phys8(nt * 16 + mh, 4 + quad) * 8);
#pragma unroll
            for (int rt = 0; rt < 2; ++rt) {
                S[rt][nt] = __builtin_amdgcn_mfma_f32_16x16x32_f16(
                    qf[rt][0], kf0, (f32x4){0.f, 0.f, 0.f, 0.f}, 0, 0, 0);
                S[rt][nt] = __builtin_amdgcn_mfma_f32_16x16x32_f16(
                    qf[rt][1], kf1, S[rt][nt], 0, 0, 0);
            }
        }
#pragma unroll
        for (int nt = 0; nt < 4; ++nt) {
            const float mv = maskb[jt + nt * 16 + mh];
#pragma unroll
            for (int rt = 0; rt < 2; ++rt)
#pragma unroll
                for (int r = 0; r < 4; ++r) {
                    float e = __expf(S[rt][nt][r] + mv - bndr[rt][r]);
                    lsum[rt][r] += e;
                    Ps[w][(rt * 16 + quad * 4 + r) * 68 + nt * 16 + mh] = (f16)e;
                }
        }
        f16x8 pf[2][2];
#pragma unroll
        for (int rt = 0; rt < 2; ++rt)
#pragma unroll
            for (int ks = 0; ks < 2; ++ks)
                pf[rt][ks] = *(const f16x8*)(
                    &Ps[w][(rt * 16 + mh) * 68 + ks * 32 + quad * 8]);
#pragma unroll
        for (int dt = 0; dt < 4; ++dt) {
            f16x8 vf0 = *(const f16x8*)(Vb + phys8(dt * 16 + mh, 0 + quad) * 8);
            f16x8 vf1 = *(const f16x8*)(Vb + phys8(dt * 16 + mh, 4 + quad) * 8);
#pragma unroll
            for (int rt = 0; rt < 2; ++rt) {
                O[rt][dt] = __builtin_amdgcn_mfma_f32_16x16x32_f16(
                    pf[rt][0], vf0, O[rt][dt], 0, 0, 0);
                O[rt][dt] = __builtin_amdgcn_mfma_f32_16x16x32_f16(
                    pf[rt][1], vf1, O[rt][dt], 0, 0, 0);
            }
        }
    };

    __syncthreads();   // tile 0 landed

    for (int jt = 0; jt < kS; jt += 128) {
        issue(Ks[1], Vs[1]);               // prefetch tile jt+64
        step(Ks[0], Vs[0], jt);            // compute tile jt (overlaps)
        __syncthreads();                   // drain prefetch; all done w/ buf0
        if (jt + 128 < kS) issue(Ks[0], Vs[0]);   // prefetch tile jt+128
        step(Ks[1], Vs[1], jt + 64);       // compute tile jt+64 (overlaps)
        __syncthreads();
    }

    // final l reduction + write
#pragma unroll
    for (int rt = 0; rt < 2; ++rt)
#pragma unroll
        for (int r = 0; r < 4; ++r) {
#pragma unroll
            for (int off = 1; off < 16; off <<= 1)
                lsum[rt][r] += __shfl_xor(lsum[rt][r], off, 64);
            lsum[rt][r] = 1.0f / lsum[rt][r];
        }
#pragma unroll
    for (int rt = 0; rt < 2; ++rt)
#pragma unroll
        for (int dt = 0; dt < 4; ++dt)
#pragma unroll
            for (int r = 0; r < 4; ++r) {
                const int s = q0 + w * 32 + rt * 16 + quad * 4 + r;
                out[((size_t)(bbb * kS + s)) * kH + (h << 6) + dt * 16 + mh] =
                    O[rt][dt][r] * lsum[rt][r];
            }
}

// ---------------------------------------------------------------------------
extern "C" void kernel_launch(void* const* d_in, const int* in_sizes, int n_in,
                              void* d_out, int out_size, void* d_ws, size_t ws_size,
                              hipStream_t stream) {
    (void)in_sizes; (void)n_in; (void)out_size; (void)ws_size;

    const float* hs   = (const float*)d_in[0];
    const float* mask = (const float*)d_in[1];
    const float* ce   = (const float*)d_in[2];
    const float* Wq   = (const float*)d_in[3];
    const float* bq   = (const float*)d_in[4];
    const float* Wk   = (const float*)d_in[5];
    const float* bk   = (const float*)d_in[6];
    const float* Wv   = (const float*)d_in[7];
    const float* bv   = (const float*)d_in[8];
    const float* Wcq  = (const float*)d_in[9];
    const float* bcq  = (const float*)d_in[10];
    const float* Wck  = (const float*)d_in[11];
    const float* bck  = (const float*)d_in[12];
    const float* wlqc = (const float*)d_in[13];
    const float* wlqq = (const float*)d_in[14];
    const float* wlkc = (const float*)d_in[15];
    const float* wlkk = (const float*)d_in[16];
    float* out = (float*)d_out;

    f16* hs16 = (f16*)d_ws;                            // 16.78 MB
    f16* Wt   = hs16 + (size_t)kB * kS * kH;           // 6.29 MB
    f16* q16  = Wt + (size_t)3 * kH * kH;              // 16.78 MB
    f16* k16  = q16 + (size_t)kRows * kHD;             // 16.78 MB
    f16* vt   = k16 + (size_t)kRows * kHD;             // 16.78 MB  [bh][d][s]
    f16* ce16 = vt + (size_t)kRows * kHD;              // 16.78 MB  [bh][s][d]
    f16* Wct  = ce16 + (size_t)kRows * kHD;            // 16 KB
    unsigned int* kn = (unsigned int*)(Wct + 2 * kHD * kHD);  // 128 u32
    float* mm = (float*)(kn + kBH);                    // 8 f32

    hipMemsetAsync(kn, 0, kBH * sizeof(unsigned int), stream);

    cast_inputs_kernel<<<dim3(kB * kS * kH / (256 * 8), 2), 256, 0, stream>>>(
        hs, ce, hs16, ce16);
    transpose_w_kernel<<<dim3(16, 16, 3), 256, 0, stream>>>(Wq, Wk, Wv, Wt);
    transpose_wc_kernel<<<dim3(2), 256, 0, stream>>>(Wcq, Wck, Wct);
    maskmax_kernel<<<dim3(kB), 256, 0, stream>>>(mask, mm);

    qkv_gemm_f16<<<dim3(kB * kS / 128, kH / 128, 3), 256, 0, stream>>>(
        hs16, Wt, bq, bk, bv, q16, k16, vt);

    gate_mfma<<<dim3(1024), 256, 0, stream>>>(
        ce16, Wct, bcq, bck, wlqc, wlqq, wlkc, wlkk, q16, k16, kn);

    attn_f16<<<dim3(kBH, kS / 128), 256, 0, stream>>>(
        q16, k16, vt, mask, kn, mm, out);
}

// Round 7
// 310.679 us; speedup vs baseline: 4.8079x; 1.0280x over previous
//
#include <hip/hip_runtime.h>

typedef _Float16 f16;
typedef f16   f16x8 __attribute__((ext_vector_type(8)));
typedef float f32x4 __attribute__((ext_vector_type(4)));

namespace {
constexpr int kB  = 8;
constexpr int kS  = 1024;
constexpr int kH  = 1024;
constexpr int kNH = 16;
constexpr int kHD = 64;
constexpr int kBH = kB * kNH;            // 128
constexpr int kRows = kBH * kS;          // 131072
}

// async global->LDS, 16B per lane; LDS dest = wave-uniform base + lane*16
__device__ __forceinline__ void async16(const f16* g, f16* l) {
    __builtin_amdgcn_global_load_lds(
        (const __attribute__((address_space(1))) unsigned int*)g,
        (__attribute__((address_space(3))) unsigned int*)l, 16, 0, 0);
}

// --- LDS chunk swizzles (16B chunks). Uniform bank-slot histogram per quad
// for MFMA fragment reads; invertible for global_load_lds staging. ---
__device__ __forceinline__ int phys4(int m, int c) {
    return ((m >> 1) << 3) | ((((m & 1) << 2) | c) ^ ((m >> 1) & 7));
}
__device__ __forceinline__ int phys8(int m, int c) {
    return (m << 3) | (c ^ (m & 7));
}

// ---------------------------------------------------------------------------
// Merged input casts: y=0 hs fp32 -> f16 flat; y=1 ce fp32 -> f16 head-split
// ---------------------------------------------------------------------------
__global__ __launch_bounds__(256) void cast_inputs_kernel(
    const float* __restrict__ hs, const float* __restrict__ ce,
    f16* __restrict__ hs16, f16* __restrict__ ce16)
{
    int i = (blockIdx.x * 256 + threadIdx.x) * 8;
    const float* src = blockIdx.y ? ce : hs;
    float4 a = *(const float4*)(src + i);
    float4 b = *(const float4*)(src + i + 4);
    union { f16 h[8]; uint4 u; } pk;
    pk.h[0] = (f16)a.x; pk.h[1] = (f16)a.y; pk.h[2] = (f16)a.z; pk.h[3] = (f16)a.w;
    pk.h[4] = (f16)b.x; pk.h[5] = (f16)b.y; pk.h[6] = (f16)b.z; pk.h[7] = (f16)b.w;
    if (blockIdx.y == 0) {
        *(uint4*)(hs16 + i) = pk.u;
    } else {
        int row = i >> 10, col = i & 1023;
        int bb = row >> 10, s = row & 1023;
        int h = col >> 6, d = col & 63;
        size_t o = ((((size_t)(bb * kNH + h) << 10) | s) << 6) | d;
        *(uint4*)(ce16 + o) = pk.u;
    }
}

// ---------------------------------------------------------------------------
// Transpose+cast W [K][N] fp32 -> Wt [N][K] f16
// ---------------------------------------------------------------------------
__global__ __launch_bounds__(256) void transpose_w_kernel(
    const float* __restrict__ Wq, const float* __restrict__ Wk,
    const float* __restrict__ Wv, f16* __restrict__ Wt)
{
    const float* W = (blockIdx.z == 0) ? Wq : (blockIdx.z == 1) ? Wk : Wv;
    f16* out = Wt + (size_t)blockIdx.z * kH * kH;
    __shared__ f16 T[64][72];
    const int tid = threadIdx.x;
    const int k0 = blockIdx.y * 64, n0 = blockIdx.x * 64;
#pragma unroll
    for (int i = 0; i < 4; ++i) {
        int idx = tid + i * 256;
        int r = idx >> 4, cb = (idx & 15) * 4;
        float4 v = *(const float4*)(W + (size_t)(k0 + r) * kH + n0 + cb);
        T[cb + 0][r] = (f16)v.x; T[cb + 1][r] = (f16)v.y;
        T[cb + 2][r] = (f16)v.z; T[cb + 3][r] = (f16)v.w;
    }
    __syncthreads();
#pragma unroll
    for (int i = 0; i < 4; ++i) {
        int idx = tid + i * 256;
        int r = idx >> 4, cb = (idx & 15) * 4;
        union { f16 h[4]; uint2 u; } pk;
#pragma unroll
        for (int j = 0; j < 4; ++j) pk.h[j] = T[r][cb + j];
        *(uint2*)(out + (size_t)(n0 + r) * kH + k0 + cb) = pk.u;
    }
}

// ---------------------------------------------------------------------------
// Small prep, one launch: blocks 0-1 transpose Wcq/Wck fp32 -> f16 [n][k]
// (block 0 also zeroes kn); blocks 2-9 compute per-batch mask max.
// ---------------------------------------------------------------------------
__global__ __launch_bounds__(256) void prep_small_kernel(
    const float* __restrict__ Wcq, const float* __restrict__ Wck,
    const float* __restrict__ mask,
    f16* __restrict__ Wct, unsigned int* __restrict__ kn,
    float* __restrict__ mm)
{
    const int t = threadIdx.x;
    if (blockIdx.x < 2) {
        const float* W = blockIdx.x ? Wck : Wcq;
        f16* out = Wct + blockIdx.x * kHD * kHD;
#pragma unroll
        for (int i = 0; i < 16; ++i) {
            int idx = i * 256 + t;
            int k = idx >> 6, n = idx & 63;
            out[n * 64 + k] = (f16)W[idx];
        }
        if (blockIdx.x == 0 && t < kBH) kn[t] = 0u;
    } else {
        const int b = blockIdx.x - 2;
        const float* mp = mask + b * kS;
        float v = fmaxf(fmaxf(mp[t], mp[t + 256]), fmaxf(mp[t + 512], mp[t + 768]));
#pragma unroll
        for (int off = 1; off < 64; off <<= 1) v = fmaxf(v, __shfl_xor(v, off, 64));
        __shared__ float red[4];
        if ((t & 63) == 0) red[t >> 6] = v;
        __syncthreads();
        if (t == 0) mm[b] = fmaxf(fmaxf(red[0], red[1]), fmaxf(red[2], red[3]));
    }
}

// ---------------------------------------------------------------------------
// QKV GEMM, f16 MFMA, K-loop DOUBLE-BUFFERED (one barrier per k-step;
// prefetch of tile t+1 in flight across a full 16-MFMA compute phase).
// Epilogue bounce Cb aliases the staging LDS (dead after final barrier).
// ---------------------------------------------------------------------------
__global__ __launch_bounds__(256) void qkv_gemm_f16(
    const f16* __restrict__ hs16, const f16* __restrict__ Wt,
    const float* __restrict__ bq, const float* __restrict__ bk,
    const float* __restrict__ bv,
    f16* __restrict__ q16, f16* __restrict__ k16, f16* __restrict__ vt)
{
    const int z = blockIdx.z;
    const f16* Bmat = Wt + (size_t)z * kH * kH;
    const float* bias = (z == 0) ? bq : (z == 1) ? bk : bv;

    __shared__ f16 AB[2][2][128 * 32];   // [buf][A=0/B=1]

    const int tid = threadIdx.x;
    const int w = tid >> 6, lane = tid & 63;
    const int quad = lane >> 4, mh = lane & 15;
    const int wm = w >> 1, wn = w & 1;
    const int m0 = blockIdx.x * 128, n0 = blockIdx.y * 128;

    const f16* aptr[2]; const f16* bptr[2];
#pragma unroll
    for (int i = 0; i < 2; ++i) {
        int P = (w * 2 + i) * 64 + lane;
        int r2 = P >> 3, s = P & 7;
        int bb = s ^ (r2 & 7);
        int m = (r2 << 1) | (bb >> 2), c = bb & 3;
        aptr[i] = hs16 + (size_t)(m0 + m) * kH + c * 8;
        bptr[i] = Bmat + (size_t)(n0 + m) * kH + c * 8;
    }

    auto issue = [&](int buf) {
#pragma unroll
        for (int i = 0; i < 2; ++i) {
            async16(aptr[i], AB[buf][0] + (w * 2 + i) * 512);
            async16(bptr[i], AB[buf][1] + (w * 2 + i) * 512);
            aptr[i] += 32; bptr[i] += 32;
        }
    };

    f32x4 acc[4][4];
#pragma unroll
    for (int i = 0; i < 4; ++i)
#pragma unroll
        for (int j = 0; j < 4; ++j) acc[i][j] = (f32x4){0.f, 0.f, 0.f, 0.f};

    int aoff[4], boff[4];
#pragma unroll
    for (int t = 0; t < 4; ++t) {
        aoff[t] = phys4(wm * 64 + t * 16 + mh, quad) * 8;
        boff[t] = phys4(wn * 64 + t * 16 + mh, quad) * 8;
    }

    auto compute = [&](int buf) {
        f16x8 af[4], bf[4];
#pragma unroll
        for (int t = 0; t < 4; ++t) af[t] = *(const f16x8*)(AB[buf][0] + aoff[t]);
#pragma unroll
        for (int t = 0; t < 4; ++t) bf[t] = *(const f16x8*)(AB[buf][1] + boff[t]);
#pragma unroll
        for (int i = 0; i < 4; ++i)
#pragma unroll
            for (int j = 0; j < 4; ++j)
                acc[i][j] = __builtin_amdgcn_mfma_f32_16x16x32_f16(
                    af[i], bf[j], acc[i][j], 0, 0, 0);
    };

    issue(0);                 // tile 0
    __syncthreads();

    for (int it = 0; it < 16; ++it) {
        issue(1);             // prefetch tile 2it+1 (overlaps compute)
        compute(0);           // tile 2it
        __syncthreads();      // drain prefetch; buf0 free
        if (it < 15) issue(0);  // prefetch tile 2it+2
        compute(1);           // tile 2it+1
        __syncthreads();
    }

    if (z < 2) {
        f16* outp = (z == 0) ? q16 : k16;
        f16* Cb = &AB[0][0][0] + w * 1280;   // per-wave 64x20 bounce (aliased)
        const int h    = (n0 + wn * 64) >> 6;
        const int bbb  = m0 >> 10;
        const int sb   = (m0 & 1023) + wm * 64;
        f16* base = outp + ((size_t)(bbb * kNH + h) * kS + sb) * kHD;
#pragma unroll
        for (int nt = 0; nt < 4; ++nt) {
            const float bn = bias[n0 + wn * 64 + nt * 16 + mh];
#pragma unroll
            for (int mt = 0; mt < 4; ++mt)
#pragma unroll
                for (int r = 0; r < 4; ++r)
                    Cb[(mt * 16 + quad * 4 + r) * 20 + mh] =
                        (f16)(acc[mt][nt][r] + bn);
#pragma unroll
            for (int p = 0; p < 4; ++p) {
                int row = (lane >> 2) + p * 16;
                int qtr = lane & 3;
                uint2 v = *(const uint2*)(&Cb[row * 20 + qtr * 4]);
                *(uint2*)(base + (size_t)row * kHD + nt * 16 + qtr * 4) = v;
            }
        }
    } else {
#pragma unroll
        for (int nt = 0; nt < 4; ++nt) {
            const int n = n0 + wn * 64 + nt * 16 + mh;
            const int h = n >> 6, d = n & 63;
            const float bn = bias[n];
#pragma unroll
            for (int mt = 0; mt < 4; ++mt) {
                int mbase = m0 + wm * 64 + mt * 16 + quad * 4;
                int bbb = mbase >> 10, s0 = mbase & 1023;
                union { f16 h4[4]; uint2 u; } pk;
#pragma unroll
                for (int r = 0; r < 4; ++r) pk.h4[r] = (f16)(acc[mt][nt][r] + bn);
                *(uint2*)(vt + ((size_t)(bbb * kNH + h) * kHD + d) * kS + s0) = pk.u;
            }
        }
    }
}

// ---------------------------------------------------------------------------
// Context gating, MFMA (unchanged). Also computes max |k_ctx|^2 per bh.
// ---------------------------------------------------------------------------
__global__ __launch_bounds__(256) void gate_mfma(
    const f16* __restrict__ ce16, const f16* __restrict__ Wct,
    const float* __restrict__ bcq, const float* __restrict__ bck,
    const float* __restrict__ wlqc, const float* __restrict__ wlqq,
    const float* __restrict__ wlkc, const float* __restrict__ wlkk,
    f16* __restrict__ q16, f16* __restrict__ k16,
    unsigned int* __restrict__ kn)
{
    __shared__ f16 Wls[64 * 64];
    __shared__ f16 CeQ[4][64 * 64];
    __shared__ float Tp[4][64 * 17];
    __shared__ float lamS[4][64];

    const int tid = threadIdx.x, w = tid >> 6, lane = tid & 63;
    const int quad = lane >> 4, mh = lane & 15;
    const int gate = blockIdx.x >> 9;
    const int tIdx = (blockIdx.x & 511) * 4 + w;
    const size_t row0 = (size_t)tIdx * 64;

    const float* bc  = gate ? bck  : bcq;
    const float* wlc = gate ? wlkc : wlqc;
    const float* wlx = gate ? wlkk : wlqq;
    f16* xw = (gate ? k16 : q16) + row0 * kHD;
    const f16* cep = ce16 + row0 * kHD;
    const f16* Wcg = Wct + gate * kHD * kHD;

#pragma unroll
    for (int i = 0; i < 2; ++i) {
        int P = tid + i * 256;
        int m = P >> 3, c = P & 7;
        *(uint4*)(Wls + phys8(m, c) * 8) = *(const uint4*)(Wcg + m * 64 + c * 8);
    }
#pragma unroll
    for (int i = 0; i < 8; ++i) {
        int P = i * 64 + lane;
        int m = P >> 3, c = (P & 7) ^ (m & 7);
        async16(cep + m * 64 + c * 8, CeQ[w] + i * 512);
    }
    __syncthreads();

#pragma unroll
    for (int it = 0; it < 8; ++it) {
        int slot = it * 64 + lane;
        int r = slot >> 3, c = slot & 7;
        union { uint4 u; f16 h[8]; } xv;
        xv.u = *(const uint4*)(xw + r * 64 + c * 8);
        float4 wa = ((const float4*)wlx)[c * 2];
        float4 wb = ((const float4*)wlx)[c * 2 + 1];
        float s = (float)xv.h[0] * wa.x + (float)xv.h[1] * wa.y +
                  (float)xv.h[2] * wa.z + (float)xv.h[3] * wa.w +
                  (float)xv.h[4] * wb.x + (float)xv.h[5] * wb.y +
                  (float)xv.h[6] * wb.z + (float)xv.h[7] * wb.w;
        s += __shfl_xor(s, 1, 64);
        s += __shfl_xor(s, 2, 64);
        s += __shfl_xor(s, 4, 64);
        if ((lane & 7) == 0) Tp[w][r * 17 + 16] = s;
    }

    f32x4 acc[4][4];
#pragma unroll
    for (int i = 0; i < 4; ++i)
#pragma unroll
        for (int j = 0; j < 4; ++j) acc[i][j] = (f32x4){0.f, 0.f, 0.f, 0.f};

    f16x8 bfr[4][2];
#pragma unroll
    for (int nt = 0; nt < 4; ++nt)
#pragma unroll
        for (int ks = 0; ks < 2; ++ks)
            bfr[nt][ks] = *(const f16x8*)(Wls + phys8(nt * 16 + mh, ks * 4 + quad) * 8);
#pragma unroll
    for (int mt = 0; mt < 4; ++mt) {
        f16x8 a0 = *(const f16x8*)(CeQ[w] + phys8(mt * 16 + mh, 0 + quad) * 8);
        f16x8 a1 = *(const f16x8*)(CeQ[w] + phys8(mt * 16 + mh, 4 + quad) * 8);
#pragma unroll
        for (int nt = 0; nt < 4; ++nt) {
            acc[mt][nt] = __builtin_amdgcn_mfma_f32_16x16x32_f16(a0, bfr[nt][0], acc[mt][nt], 0, 0, 0);
            acc[mt][nt] = __builtin_amdgcn_mfma_f32_16x16x32_f16(a1, bfr[nt][1], acc[mt][nt], 0, 0, 0);
        }
    }

    float bcv[4], wlcv[4];
#pragma unroll
    for (int nt = 0; nt < 4; ++nt) {
        int n = nt * 16 + mh;
        bcv[nt] = bc[n]; wlcv[nt] = wlc[n];
    }
#pragma unroll
    for (int mt = 0; mt < 4; ++mt) {
#pragma unroll
        for (int r = 0; r < 4; ++r) {
            int m = mt * 16 + quad * 4 + r;
            float tpv = 0.f;
#pragma unroll
            for (int nt = 0; nt < 4; ++nt) {
                float v = acc[mt][nt][r] + bcv[nt];
                int col = nt * 16 + mh;
                CeQ[w][phys8(m, col >> 3) * 8 + (col & 7)] = (f16)v;
                tpv += v * wlcv[nt];
            }
            Tp[w][m * 17 + mh] = tpv;
        }
    }

    float t = 0.f;
#pragma unroll
    for (int j = 0; j < 17; ++j) t += Tp[w][lane * 17 + j];
    lamS[w][lane] = 1.0f / (1.0f + __expf(-t));

    float wmax = 0.f;
#pragma unroll
    for (int it = 0; it < 8; ++it) {
        int slot = it * 64 + lane;
        int r = slot >> 3, c = slot & 7;
        float lam = lamS[w][r];
        union { uint4 u; f16 h[8]; } xv;
        xv.u = *(const uint4*)(xw + r * 64 + c * 8);
        f16x8 cq = *(const f16x8*)(CeQ[w] + phys8(r, c) * 8);
        union { f16 h[8]; uint4 u; } o;
        float ss = 0.f;
#pragma unroll
        for (int j = 0; j < 8; ++j) {
            o.h[j] = (f16)((1.0f - lam) * (float)xv.h[j] + lam * (float)cq[j]);
            float fv = (float)o.h[j];
            ss += fv * fv;
        }
        *(uint4*)(xw + r * 64 + c * 8) = o.u;
        if (gate) {
            ss += __shfl_xor(ss, 1, 64);
            ss += __shfl_xor(ss, 2, 64);
            ss += __shfl_xor(ss, 4, 64);
            wmax = fmaxf(wmax, ss);
        }
    }
    if (gate) {
        wmax = fmaxf(wmax, __shfl_xor(wmax, 8, 64));
        wmax = fmaxf(wmax, __shfl_xor(wmax, 16, 64));
        wmax = fmaxf(wmax, __shfl_xor(wmax, 32, 64));
        if (lane == 0) atomicMax(&kn[tIdx >> 4], __float_as_uint(wmax));
    }
}

// ---------------------------------------------------------------------------
// MFMA flash attention, bound-softmax, R=2, K/V double-buffered,
// XCD-affine grid (unchanged from round 6).
// ---------------------------------------------------------------------------
__global__ __launch_bounds__(256) void attn_f16(
    const f16* __restrict__ q16, const f16* __restrict__ k16,
    const f16* __restrict__ vt, const float* __restrict__ mask,
    const unsigned int* __restrict__ kn, const float* __restrict__ mm,
    float* __restrict__ out)
{
    __shared__ f16 Ks[2][64 * 64];
    __shared__ f16 Vs[2][64 * 64];
    __shared__ f16 Ps[4][32 * 68];

    const int tid = threadIdx.x;
    const int w = tid >> 6, lane = tid & 63;
    const int quad = lane >> 4, mh = lane & 15;
    const int bh = blockIdx.x, bbb = bh >> 4, h = bh & 15;
    const int q0 = blockIdx.y * 128;
    const float* maskb = mask + bbb * kS;

    int mS[2], cS[2];
#pragma unroll
    for (int i = 0; i < 2; ++i) {
        int P = (w * 2 + i) * 64 + lane;
        mS[i] = P >> 3;
        cS[i] = (P & 7) ^ (mS[i] & 7);
    }
    const f16* kp[2]; const f16* vp[2];
#pragma unroll
    for (int i = 0; i < 2; ++i) {
        kp[i] = k16 + ((size_t)bh * kS + mS[i]) * kHD + cS[i] * 8;
        vp[i] = vt  + ((size_t)bh * kHD + mS[i]) * kS + cS[i] * 8;
    }

    auto issue = [&](f16* Kb, f16* Vb) {
#pragma unroll
        for (int i = 0; i < 2; ++i) {
            async16(kp[i], Kb + (w * 2 + i) * 512);
            async16(vp[i], Vb + (w * 2 + i) * 512);
            kp[i] += 64 * kHD;
            vp[i] += 64;
        }
    };

    issue(Ks[0], Vs[0]);

    f16x8 qf[2][2];
#pragma unroll
    for (int rt = 0; rt < 2; ++rt) {
        const f16* qrow = q16 + ((size_t)bh * kS + q0 + w * 32 + rt * 16 + mh) * kHD;
#pragma unroll
        for (int ks = 0; ks < 2; ++ks) {
            qf[rt][ks] = *(const f16x8*)(qrow + ks * 32 + quad * 8);
#pragma unroll
            for (int j = 0; j < 8; ++j) qf[rt][ks][j] *= (f16)0.125f;
        }
    }

    const float kn2 = __uint_as_float(kn[bh]);
    const float mmb = mm[bbb];
    float bndr[2][4];
#pragma unroll
    for (int rt = 0; rt < 2; ++rt) {
        float qn2 = 0.f;
#pragma unroll
        for (int ks = 0; ks < 2; ++ks)
#pragma unroll
            for (int j = 0; j < 8; ++j) {
                float v = (float)qf[rt][ks][j];
                qn2 += v * v;
            }
        qn2 += __shfl_xor(qn2, 16, 64);
        qn2 += __shfl_xor(qn2, 32, 64);
        const float bnd = sqrtf(qn2 * kn2) + mmb - 9.5f;
#pragma unroll
        for (int r = 0; r < 4; ++r) bndr[rt][r] = __shfl(bnd, quad * 4 + r, 64);
    }

    f32x4 O[2][4];
#pragma unroll
    for (int rt = 0; rt < 2; ++rt)
#pragma unroll
        for (int i = 0; i < 4; ++i) O[rt][i] = (f32x4){0.f, 0.f, 0.f, 0.f};
    float lsum[2][4] = {{0.f, 0.f, 0.f, 0.f}, {0.f, 0.f, 0.f, 0.f}};

    auto step = [&](const f16* Kb, const f16* Vb, int jt) {
        f32x4 S[2][4];
#pragma unroll
        for (int nt = 0; nt < 4; ++nt) {
            f16x8 kf0 = *(const f16x8*)(Kb + phys8(nt * 16 + mh, 0 + quad) * 8);
            f16x8 kf1 = *(const f16x8*)(Kb + phys8(nt * 16 + mh, 4 + quad) * 8);
#pragma unroll
            for (int rt = 0; rt < 2; ++rt) {
                S[rt][nt] = __builtin_amdgcn_mfma_f32_16x16x32_f16(
                    qf[rt][0], kf0, (f32x4){0.f, 0.f, 0.f, 0.f}, 0, 0, 0);
                S[rt][nt] = __builtin_amdgcn_mfma_f32_16x16x32_f16(
                    qf[rt][1], kf1, S[rt][nt], 0, 0, 0);
            }
        }
#pragma unroll
        for (int nt = 0; nt < 4; ++nt) {
            const float mv = maskb[jt + nt * 16 + mh];
#pragma unroll
            for (int rt = 0; rt < 2; ++rt)
#pragma unroll
                for (int r = 0; r < 4; ++r) {
                    float e = __expf(S[rt][nt][r] + mv - bndr[rt][r]);
                    lsum[rt][r] += e;
                    Ps[w][(rt * 16 + quad * 4 + r) * 68 + nt * 16 + mh] = (f16)e;
                }
        }
        f16x8 pf[2][2];
#pragma unroll
        for (int rt = 0; rt < 2; ++rt)
#pragma unroll
            for (int ks = 0; ks < 2; ++ks)
                pf[rt][ks] = *(const f16x8*)(
                    &Ps[w][(rt * 16 + mh) * 68 + ks * 32 + quad * 8]);
#pragma unroll
        for (int dt = 0; dt < 4; ++dt) {
            f16x8 vf0 = *(const f16x8*)(Vb + phys8(dt * 16 + mh, 0 + quad) * 8);
            f16x8 vf1 = *(const f16x8*)(Vb + phys8(dt * 16 + mh, 4 + quad) * 8);
#pragma unroll
            for (int rt = 0; rt < 2; ++rt) {
                O[rt][dt] = __builtin_amdgcn_mfma_f32_16x16x32_f16(
                    pf[rt][0], vf0, O[rt][dt], 0, 0, 0);
                O[rt][dt] = __builtin_amdgcn_mfma_f32_16x16x32_f16(
                    pf[rt][1], vf1, O[rt][dt], 0, 0, 0);
            }
        }
    };

    __syncthreads();

    for (int jt = 0; jt < kS; jt += 128) {
        issue(Ks[1], Vs[1]);
        step(Ks[0], Vs[0], jt);
        __syncthreads();
        if (jt + 128 < kS) issue(Ks[0], Vs[0]);
        step(Ks[1], Vs[1], jt + 64);
        __syncthreads();
    }

#pragma unroll
    for (int rt = 0; rt < 2; ++rt)
#pragma unroll
        for (int r = 0; r < 4; ++r) {
#pragma unroll
            for (int off = 1; off < 16; off <<= 1)
                lsum[rt][r] += __shfl_xor(lsum[rt][r], off, 64);
            lsum[rt][r] = 1.0f / lsum[rt][r];
        }
#pragma unroll
    for (int rt = 0; rt < 2; ++rt)
#pragma unroll
        for (int dt = 0; dt < 4; ++dt)
#pragma unroll
            for (int r = 0; r < 4; ++r) {
                const int s = q0 + w * 32 + rt * 16 + quad * 4 + r;
                out[((size_t)(bbb * kS + s)) * kH + (h << 6) + dt * 16 + mh] =
                    O[rt][dt][r] * lsum[rt][r];
            }
}

// ---------------------------------------------------------------------------
extern "C" void kernel_launch(void* const* d_in, const int* in_sizes, int n_in,
                              void* d_out, int out_size, void* d_ws, size_t ws_size,
                              hipStream_t stream) {
    (void)in_sizes; (void)n_in; (void)out_size; (void)ws_size;

    const float* hs   = (const float*)d_in[0];
    const float* mask = (const float*)d_in[1];
    const float* ce   = (const float*)d_in[2];
    const float* Wq   = (const float*)d_in[3];
    const float* bq   = (const float*)d_in[4];
    const float* Wk   = (const float*)d_in[5];
    const float* bk   = (const float*)d_in[6];
    const float* Wv   = (const float*)d_in[7];
    const float* bv   = (const float*)d_in[8];
    const float* Wcq  = (const float*)d_in[9];
    const float* bcq  = (const float*)d_in[10];
    const float* Wck  = (const float*)d_in[11];
    const float* bck  = (const float*)d_in[12];
    const float* wlqc = (const float*)d_in[13];
    const float* wlqq = (const float*)d_in[14];
    const float* wlkc = (const float*)d_in[15];
    const float* wlkk = (const float*)d_in[16];
    float* out = (float*)d_out;

    f16* hs16 = (f16*)d_ws;                            // 16.78 MB
    f16* Wt   = hs16 + (size_t)kB * kS * kH;           // 6.29 MB
    f16* q16  = Wt + (size_t)3 * kH * kH;              // 16.78 MB
    f16* k16  = q16 + (size_t)kRows * kHD;             // 16.78 MB
    f16* vt   = k16 + (size_t)kRows * kHD;             // 16.78 MB  [bh][d][s]
    f16* ce16 = vt + (size_t)kRows * kHD;              // 16.78 MB  [bh][s][d]
    f16* Wct  = ce16 + (size_t)kRows * kHD;            // 16 KB
    unsigned int* kn = (unsigned int*)(Wct + 2 * kHD * kHD);  // 128 u32
    float* mm = (float*)(kn + kBH);                    // 8 f32

    cast_inputs_kernel<<<dim3(kB * kS * kH / (256 * 8), 2), 256, 0, stream>>>(
        hs, ce, hs16, ce16);
    transpose_w_kernel<<<dim3(16, 16, 3), 256, 0, stream>>>(Wq, Wk, Wv, Wt);
    prep_small_kernel<<<dim3(10), 256, 0, stream>>>(Wcq, Wck, mask, Wct, kn, mm);

    qkv_gemm_f16<<<dim3(kB * kS / 128, kH / 128, 3), 256, 0, stream>>>(
        hs16, Wt, bq, bk, bv, q16, k16, vt);

    gate_mfma<<<dim3(1024), 256, 0, stream>>>(
        ce16, Wct, bcq, bck, wlqc, wlqq, wlkc, wlkk, q16, k16, kn);

    attn_f16<<<dim3(kBH, kS / 128), 256, 0, stream>>>(
        q16, k16, vt, mask, kn, mm, out);
}